// Round 1
// baseline (12008.714 us; speedup 1.0000x reference)
//
#include <hip/hip_runtime.h>
#include <math.h>

#define B_   64
#define S_   255
#define SP   256
#define D_   512
#define H_   8
#define DKD  64
#define L_   6
#define FF_  2048
#define HID_ 256
#define N_   (B_*SP)       // 16384 rows
#define EPS  1e-5f

// ---------------------------------------------------------------- utilities
__device__ inline float wave_sum(float v) {
#pragma unroll
    for (int off = 32; off; off >>= 1) v += __shfl_xor(v, off);
    return v;
}

__device__ inline float gelu_exact(float x) {
    return 0.5f * x * (1.0f + erff(x * 0.70710678118654752f));
}

// ---------------------------------------------------------------- build X = [cls; atom]
__global__ void k_build_x(const float* __restrict__ atom, const float* __restrict__ cls,
                          float* __restrict__ X) {
    int idx = blockIdx.x * 256 + threadIdx.x;      // over N_*D_
    int col = idx & (D_ - 1);
    int row = idx >> 9;
    int sr  = row & (SP - 1);
    int b   = row >> 8;
    X[idx] = (sr == 0) ? cls[col] : atom[((size_t)(b * S_) + (sr - 1)) * D_ + col];
}

// ---------------------------------------------------------------- mask layout detection
// bool input may be stored as 1 byte/elem or int32/elem. If int32, every word is 0/1.
// If bytes, the trailing run of 'true' bytes makes some word > 1 (e.g. 0x01010101).
__global__ void k_mask_detect(const unsigned int* __restrict__ mw, int nw, int* flag) {
    int i = blockIdx.x * 256 + threadIdx.x;
    if (i < nw && mw[i] > 1u) atomicOr(flag, 1);
}

__global__ void k_mask_prep(const void* __restrict__ mraw, const int* __restrict__ flag,
                            unsigned char* __restrict__ mc) {
    int i = blockIdx.x * 256 + threadIdx.x;        // over B_*SP
    int b = i >> 8, j = i & 255;
    unsigned char v = 0;
    if (j > 0) {
        int src = b * S_ + (j - 1);
        if (*flag) v = ((const unsigned char*)mraw)[src] ? 1 : 0;
        else       v = ((const int*)mraw)[src] ? 1 : 0;
    }
    mc[i] = v;
}

// ---------------------------------------------------------------- tiled f32 GEMM
// C[N][512] = A[N][K] @ W[K][M-slice] (+bias) (opt gelu) (opt +=)
// grid: (M/64, N/64), 256 threads, 4x4 per thread. flags: 1=gelu, 2=accumulate.
#define BKG 16
#define LDT 68
__global__ __launch_bounds__(256) void k_gemm(const float* __restrict__ A,
                                              const float* __restrict__ W,
                                              const float* __restrict__ bias,
                                              float* __restrict__ C,
                                              int K, int ldw, int flags) {
    __shared__ __align__(16) float As[BKG][LDT];
    __shared__ __align__(16) float Ws[BKG][LDT];
    int tid = threadIdx.x;
    int tx = tid & 15, ty = tid >> 4;
    int rowbase = blockIdx.y * 64;
    int colbase = blockIdx.x * 64;
    float acc[4][4] = {};
    for (int k0 = 0; k0 < K; k0 += BKG) {
#pragma unroll
        for (int p = 0; p < 4; p++) {
            int idx = tid + p * 256;
            int c = idx & 15, r = idx >> 4;
            As[c][r] = A[(size_t)(rowbase + r) * K + k0 + c];
        }
#pragma unroll
        for (int p = 0; p < 4; p++) {
            int idx = tid + p * 256;
            int cc = idx & 63, kk = idx >> 6;
            Ws[kk][cc] = W[(size_t)(k0 + kk) * ldw + colbase + cc];
        }
        __syncthreads();
#pragma unroll
        for (int k = 0; k < BKG; k++) {
            float4 a4 = *(const float4*)&As[k][ty * 4];
            float4 b4 = *(const float4*)&Ws[k][tx * 4];
            float av[4] = {a4.x, a4.y, a4.z, a4.w};
            float bv[4] = {b4.x, b4.y, b4.z, b4.w};
#pragma unroll
            for (int ii = 0; ii < 4; ii++)
#pragma unroll
                for (int jj = 0; jj < 4; jj++)
                    acc[ii][jj] = fmaf(av[ii], bv[jj], acc[ii][jj]);
        }
        __syncthreads();
    }
#pragma unroll
    for (int ii = 0; ii < 4; ii++) {
        int row = rowbase + ty * 4 + ii;
        float* cp = &C[(size_t)row * D_ + colbase + tx * 4];
        float v[4];
#pragma unroll
        for (int jj = 0; jj < 4; jj++) {
            float x = acc[ii][jj];
            if (bias) x += bias[colbase + tx * 4 + jj];
            if (flags & 1) x = gelu_exact(x);
            v[jj] = x;
        }
        if (flags & 2) {
            float4 o4 = *(const float4*)cp;
            v[0] += o4.x; v[1] += o4.y; v[2] += o4.z; v[3] += o4.w;
        }
        *(float4*)cp = make_float4(v[0], v[1], v[2], v[3]);
    }
}

// ---------------------------------------------------------------- fused attention
// grid: B_*H_ blocks, 256 threads (thread = query row). K/V staged 64 rows at a time.
__global__ __launch_bounds__(256) void k_attn(const float* __restrict__ Q,
                                              const float* __restrict__ Kb,
                                              const float* __restrict__ Vb,
                                              const float* __restrict__ eb,
                                              const unsigned char* __restrict__ mc,
                                              float* __restrict__ T) {
    __shared__ __align__(16) float Ks[64][64];
    __shared__ __align__(16) float Vs[64][64];
    int bh = blockIdx.x;
    int b = bh >> 3, h = bh & 7;
    int i = threadIdx.x;
    const float scale = 0.125f;   // 1/sqrt(64)

    float q[64];
    const float* qp = &Q[((size_t)(b << 8) + i) * D_ + h * DKD];
#pragma unroll
    for (int d4 = 0; d4 < 16; d4++) {
        float4 t = ((const float4*)qp)[d4];
        q[d4*4] = t.x; q[d4*4+1] = t.y; q[d4*4+2] = t.z; q[d4*4+3] = t.w;
    }
    float m = -INFINITY, l = 0.0f;
    float o[64] = {};

    for (int t0 = 0; t0 < SP; t0 += 64) {
        __syncthreads();
        float4* Ksf = (float4*)Ks;
        float4* Vsf = (float4*)Vs;
#pragma unroll
        for (int p = 0; p < 4; p++) {
            int idx = i + p * 256;             // 1024 float4 per tile
            int r = idx >> 4, c4 = idx & 15;
            size_t gbase = ((size_t)(b << 8) + t0 + r) * D_ + h * DKD;
            Ksf[idx] = ((const float4*)&Kb[gbase])[c4];
            Vsf[idx] = ((const float4*)&Vb[gbase])[c4];
        }
        __syncthreads();
        for (int j = 0; j < 64; j++) {
            int jj = t0 + j;
            if (mc[(b << 8) + jj]) continue;   // uniform skip of masked keys
            float dot = 0.0f;
#pragma unroll
            for (int d4 = 0; d4 < 16; d4++) {
                float4 kv = ((const float4*)&Ks[j][0])[d4];
                dot = fmaf(q[d4*4], kv.x, dot);
                dot = fmaf(q[d4*4+1], kv.y, dot);
                dot = fmaf(q[d4*4+2], kv.z, dot);
                dot = fmaf(q[d4*4+3], kv.w, dot);
            }
            float s = dot * scale;
            if (i > 0 && jj > 0)
                s += eb[((size_t)(b * S_ + (i - 1)) * S_ + (jj - 1)) * H_ + h];
            if (s > m) {
                float f = __expf(m - s);       // m=-inf -> 0
                l = l * f + 1.0f;
                m = s;
#pragma unroll
                for (int d4 = 0; d4 < 16; d4++) {
                    float4 vv = ((const float4*)&Vs[j][0])[d4];
                    o[d4*4]   = o[d4*4]  * f + vv.x;
                    o[d4*4+1] = o[d4*4+1]* f + vv.y;
                    o[d4*4+2] = o[d4*4+2]* f + vv.z;
                    o[d4*4+3] = o[d4*4+3]* f + vv.w;
                }
            } else {
                float p = __expf(s - m);
                l += p;
#pragma unroll
                for (int d4 = 0; d4 < 16; d4++) {
                    float4 vv = ((const float4*)&Vs[j][0])[d4];
                    o[d4*4]   = fmaf(p, vv.x, o[d4*4]);
                    o[d4*4+1] = fmaf(p, vv.y, o[d4*4+1]);
                    o[d4*4+2] = fmaf(p, vv.z, o[d4*4+2]);
                    o[d4*4+3] = fmaf(p, vv.w, o[d4*4+3]);
                }
            }
        }
    }
    float inv = 1.0f / l;
    float* op = &T[((size_t)(b << 8) + i) * D_ + h * DKD];
#pragma unroll
    for (int d4 = 0; d4 < 16; d4++)
        ((float4*)op)[d4] = make_float4(o[d4*4]*inv, o[d4*4+1]*inv, o[d4*4+2]*inv, o[d4*4+3]*inv);
}

// ---------------------------------------------------------------- residual + LayerNorm
// X[row] = LN(X[row] + U[row] (+pb)) * g + b
__global__ __launch_bounds__(256) void k_ln(float* __restrict__ X, const float* __restrict__ U,
                                            const float* __restrict__ pb,
                                            const float* __restrict__ g,
                                            const float* __restrict__ bb) {
    __shared__ float red[4];
    int row = blockIdx.x, t = threadIdx.x;
    size_t base = (size_t)row * D_;
    float v0 = X[base + t] + U[base + t];
    float v1 = X[base + t + 256] + U[base + t + 256];
    if (pb) { v0 += pb[t]; v1 += pb[t + 256]; }
    float s = wave_sum(v0 + v1);
    if ((t & 63) == 0) red[t >> 6] = s;
    __syncthreads();
    float mean = (red[0] + red[1] + red[2] + red[3]) * (1.0f / D_);
    float d0 = v0 - mean, d1 = v1 - mean;
    float s2 = wave_sum(d0 * d0 + d1 * d1);
    __syncthreads();
    if ((t & 63) == 0) red[t >> 6] = s2;
    __syncthreads();
    float var = (red[0] + red[1] + red[2] + red[3]) * (1.0f / D_);
    float rr = rsqrtf(var + EPS);
    X[base + t]       = d0 * rr * g[t] + bb[t];
    X[base + t + 256] = d1 * rr * g[t + 256] + bb[t + 256];
}

// ---------------------------------------------------------------- MLP head on CLS
__global__ __launch_bounds__(256) void k_head(const float* __restrict__ X,
                                              const float* __restrict__ W1,
                                              const float* __restrict__ b1,
                                              const float* __restrict__ W2,
                                              const float* __restrict__ b2,
                                              float* __restrict__ out) {
    __shared__ float cls[D_];
    __shared__ float red[4];
    int b = blockIdx.x, t = threadIdx.x;
    size_t base = (size_t)(b << 8) * D_;     // row b*256 (CLS)
    cls[t]       = X[base + t];
    cls[t + 256] = X[base + t + 256];
    __syncthreads();
    float acc = 0.0f;
    for (int d = 0; d < D_; d++) acc = fmaf(cls[d], W1[(size_t)d * HID_ + t], acc);
    acc += b1[t];
    float hsum = wave_sum(gelu_exact(acc) * W2[t]);
    if ((t & 63) == 0) red[t >> 6] = hsum;
    __syncthreads();
    if (t == 0) out[b] = red[0] + red[1] + red[2] + red[3] + b2[0];
}

// ---------------------------------------------------------------- launch
extern "C" void kernel_launch(void* const* d_in, const int* in_sizes, int n_in,
                              void* d_out, int out_size, void* d_ws, size_t ws_size,
                              hipStream_t stream) {
    const float* atom = (const float*)d_in[0];
    const float* eb   = (const float*)d_in[1];
    const void*  mraw = d_in[2];
    const float* cls  = (const float*)d_in[3];
    const float* Wq = (const float*)d_in[4];  const float* bq = (const float*)d_in[5];
    const float* Wk = (const float*)d_in[6];  const float* bk = (const float*)d_in[7];
    const float* Wv = (const float*)d_in[8];  const float* bv = (const float*)d_in[9];
    const float* Wo = (const float*)d_in[10]; const float* bo = (const float*)d_in[11];
    const float* g1 = (const float*)d_in[12]; const float* be1 = (const float*)d_in[13];
    const float* W1 = (const float*)d_in[14]; const float* b1 = (const float*)d_in[15];
    const float* W2 = (const float*)d_in[16]; const float* b2 = (const float*)d_in[17];
    const float* g2 = (const float*)d_in[18]; const float* be2 = (const float*)d_in[19];
    const float* hW1 = (const float*)d_in[20]; const float* hb1 = (const float*)d_in[21];
    const float* hW2 = (const float*)d_in[22]; const float* hb2 = (const float*)d_in[23];
    float* out = (float*)d_out;

    size_t ND = (size_t)N_ * D_;             // 8388608 floats
    float* X  = (float*)d_ws;
    float* Qb = X  + ND;
    float* Kb = Qb + ND;
    float* Vb = Kb + ND;
    float* Tb = Vb + ND;
    float* Ub = Tb + ND;
    int*   flag = (int*)(Ub + ND);
    unsigned char* mc = (unsigned char*)(flag + 1);
    // total ws use: 6*32MiB + ~16KB ≈ 192.5 MiB

    hipMemsetAsync(flag, 0, 4, stream);
    k_mask_detect<<<16, 256, 0, stream>>>((const unsigned int*)mraw, (B_ * S_) / 4, flag);
    k_mask_prep<<<(B_ * SP) / 256, 256, 0, stream>>>(mraw, flag, mc);
    k_build_x<<<(N_ * D_) / 256, 256, 0, stream>>>(atom, cls, X);

    dim3 gg(8, 256);                         // (M/64, N/64) for M=512
    for (int l = 0; l < L_; l++) {
        const float* wq = Wq + (size_t)l * D_ * D_;
        const float* wk = Wk + (size_t)l * D_ * D_;
        const float* wv = Wv + (size_t)l * D_ * D_;
        const float* wo = Wo + (size_t)l * D_ * D_;
        k_gemm<<<gg, 256, 0, stream>>>(X, wq, bq + l * D_, Qb, 512, 512, 0);
        k_gemm<<<gg, 256, 0, stream>>>(X, wk, bk + l * D_, Kb, 512, 512, 0);
        k_gemm<<<gg, 256, 0, stream>>>(X, wv, bv + l * D_, Vb, 512, 512, 0);
        k_attn<<<B_ * H_, 256, 0, stream>>>(Qb, Kb, Vb, eb, mc, Tb);
        k_gemm<<<gg, 256, 0, stream>>>(Tb, wo, bo + l * D_, Ub, 512, 512, 0);
        k_ln<<<N_, 256, 0, stream>>>(X, Ub, nullptr, g1 + l * D_, be1 + l * D_);
        for (int c = 0; c < 4; c++) {
            k_gemm<<<gg, 256, 0, stream>>>(X, W1 + (size_t)l * D_ * FF_ + c * 512,
                                           b1 + l * FF_ + c * 512, Tb, 512, FF_, 1);
            k_gemm<<<gg, 256, 0, stream>>>(Tb, W2 + ((size_t)l * FF_ + c * 512) * D_,
                                           nullptr, Ub, 512, 512, c ? 2 : 0);
        }
        k_ln<<<N_, 256, 0, stream>>>(X, Ub, b2 + l * D_, g2 + l * D_, be2 + l * D_);
    }
    k_head<<<B_, 256, 0, stream>>>(X, hW1, hb1, hW2, hb2, out);
}

// Round 2
// 2887.885 us; speedup vs baseline: 4.1583x; 4.1583x over previous
//
#include <hip/hip_runtime.h>
#include <math.h>
#include <stdint.h>

#define B_   64
#define S_   255
#define SP   256
#define D_   512
#define H_   8
#define L_   6
#define FF_  2048
#define HID_ 256
#define N_   (B_*SP)       // 16384 rows
#define EPS  1e-5f

using bf16x8 = __bf16 __attribute__((ext_vector_type(8)));
using f32x4  = float __attribute__((ext_vector_type(4)));

// ---------------------------------------------------------------- utilities
__device__ inline float wave_sum(float v) {
#pragma unroll
    for (int off = 32; off; off >>= 1) v += __shfl_xor(v, off);
    return v;
}

__device__ inline float gelu_exact(float x) {
    return 0.5f * x * (1.0f + erff(x * 0.70710678118654752f));
}

// fp8 e4m3fn encode (RNE) / decode
__device__ inline uint8_t enc_e4m3(float f) {
    uint32_t u = __float_as_uint(f);
    uint32_t s = (u >> 24) & 0x80u;
    float a = fabsf(f);
    if (a < 0.015625f) {                       // denormal range: multiples of 2^-9
        int m = (int)rintf(a * 512.0f);
        if (m >= 8) return (uint8_t)(s | 0x08);
        return (uint8_t)(s | (uint32_t)m);
    }
    if (a > 448.0f) return (uint8_t)(s | 0x7E);
    uint32_t b = __float_as_uint(a);
    uint32_t expf_ = b >> 23;                  // >= 121 here
    uint32_t mant = b & 0x7FFFFF;
    uint32_t keep = mant >> 20;
    uint32_t rest = mant & 0xFFFFF;
    if (rest > 0x80000u || (rest == 0x80000u && (keep & 1))) keep++;
    if (keep == 8) { keep = 0; expf_++; }
    int e8 = (int)expf_ - 120;
    if (e8 >= 16) return (uint8_t)(s | 0x7E);
    return (uint8_t)(s | ((uint32_t)e8 << 3) | keep);
}

__device__ inline float dec_e4m3(uint32_t b) {
    uint32_t mag = b & 0x7Fu;
    float fm = __uint_as_float((mag << 20) + (120u << 23));
    if ((mag >> 3) == 0) fm = fm * 2.0f - 0.015625f;   // denormal fix
    return (b & 0x80u) ? -fm : fm;
}

// ---------------------------------------------------------------- build X = [cls; atom]
__global__ void k_build_x(const float* __restrict__ atom, const float* __restrict__ cls,
                          float* __restrict__ X, __bf16* __restrict__ Xb) {
    int idx = blockIdx.x * 256 + threadIdx.x;      // over N_*D_
    int col = idx & (D_ - 1);
    int row = idx >> 9;
    int sr  = row & (SP - 1);
    int b   = row >> 8;
    float v = (sr == 0) ? cls[col] : atom[((size_t)(b * S_) + (sr - 1)) * D_ + col];
    X[idx]  = v;
    Xb[idx] = (__bf16)v;
}

// ---------------------------------------------------------------- mask layout detection
__global__ void k_mask_detect(const unsigned int* __restrict__ mw, int nw, int* flag) {
    int i = blockIdx.x * 256 + threadIdx.x;
    if (i < nw && mw[i] > 1u) atomicOr(flag, 1);
}

__global__ void k_mask_prep(const void* __restrict__ mraw, const int* __restrict__ flag,
                            unsigned char* __restrict__ mc) {
    int i = blockIdx.x * 256 + threadIdx.x;        // over B_*SP
    int b = i >> 8, j = i & 255;
    unsigned char v = 0;
    if (j > 0) {
        int src = b * S_ + (j - 1);
        if (*flag) v = ((const unsigned char*)mraw)[src] ? 1 : 0;
        else       v = ((const int*)mraw)[src] ? 1 : 0;
    }
    mc[i] = v;
}

// ---------------------------------------------------------------- weight transpose+cast
// W [K][Mw] f32 (layer-strided) -> Wt [mout_off+Mw][K] bf16 (layer-strided)
__global__ __launch_bounds__(256) void k_wt(const float* __restrict__ W, __bf16* __restrict__ Wt,
                                            int K, int Mw, int mout_off,
                                            size_t in_lstride, size_t out_lstride) {
    __shared__ float T[64][65];
    int l = blockIdx.z;
    int m0 = blockIdx.x * 64, k0 = blockIdx.y * 64;
    const float* Wl = W + (size_t)l * in_lstride;
    __bf16* Wtl = Wt + (size_t)l * out_lstride;
    int tid = threadIdx.x;
    int cc = tid & 63, rr = tid >> 6;
#pragma unroll
    for (int p = 0; p < 16; p++) {
        int kk = rr + p * 4;
        T[kk][cc] = Wl[(size_t)(k0 + kk) * Mw + m0 + cc];
    }
    __syncthreads();
#pragma unroll
    for (int p = 0; p < 16; p++) {
        int mm = rr + p * 4;
        Wtl[(size_t)(mout_off + m0 + mm) * K + k0 + cc] = (__bf16)T[cc][mm];
    }
}

// ---------------------------------------------------------------- qkv bias concat
__global__ void k_bcat(const float* __restrict__ bq, const float* __restrict__ bk,
                       const float* __restrict__ bv, float* __restrict__ bqkv) {
    int i = blockIdx.x * 256 + threadIdx.x;        // over 6*1536
    int l = i / 1536, c = i % 1536;
    float v;
    if (c < 512)       v = bq[l * 512 + c];
    else if (c < 1024) v = bk[l * 512 + c - 512];
    else               v = bv[l * 512 + c - 1024];
    bqkv[i] = v;
}

// ---------------------------------------------------------------- bias repack: eb -> fp8 ebt[b][h][256][256]
__global__ __launch_bounds__(256) void k_ebt(const float* __restrict__ eb, uint8_t* __restrict__ ebt) {
    __shared__ float Ls[2040];
    int blk = blockIdx.x;                          // b*256 + ii
    int b = blk >> 8, ii = blk & 255;
    int t = threadIdx.x;
    if (ii > 0) {
        const float* src = eb + ((size_t)(b * S_) + (ii - 1)) * (S_ * H_);
        for (int p = 0; p < 8; p++) {
            int idx = t + p * 256;
            if (idx < 2040) Ls[idx] = src[idx];
        }
    }
    __syncthreads();
#pragma unroll
    for (int h = 0; h < H_; h++) {
        uint8_t v = 0;
        if (ii > 0 && t > 0) v = enc_e4m3(Ls[(t - 1) * 8 + h]);
        ebt[(((size_t)(b * 8 + h)) << 16) + ((size_t)ii << 8) + t] = v;
    }
}

// ---------------------------------------------------------------- bf16 MFMA GEMM
// A [N][K] bf16 row-major; Bt [M][K] bf16 (pre-transposed weights); out [N][M]
// 128x128 tile, 4 waves (2x2 of 64x64), BK=32, f32 accumulate.
template<int OUTBF, int GELU>
__global__ __launch_bounds__(256) void k_gemm(const __bf16* __restrict__ A,
                                              const __bf16* __restrict__ Bt,
                                              const float* __restrict__ bias,
                                              float* __restrict__ C,
                                              __bf16* __restrict__ Cb,
                                              int K, int M) {
    __shared__ __align__(16) __bf16 As[128 * 32];
    __shared__ __align__(16) __bf16 Bs[128 * 32];
    const int tid = threadIdx.x;
    const int wid = tid >> 6, lane = tid & 63;
    const int rowbase = blockIdx.y * 128, colbase = blockIdx.x * 128;
    const int wr = wid >> 1, wc = wid & 1;
    const int lrow = lane & 15, lk = (lane >> 4) * 8;

    f32x4 acc[4][4];
#pragma unroll
    for (int m = 0; m < 4; m++)
#pragma unroll
        for (int n = 0; n < 4; n++) acc[m][n] = f32x4{0.f, 0.f, 0.f, 0.f};

    for (int k0 = 0; k0 < K; k0 += 32) {
#pragma unroll
        for (int p = 0; p < 2; p++) {
            int idx = tid + p * 256;               // 512 segs of 8 bf16
            int r = idx >> 2, c = idx & 3;
            *(uint4*)&As[idx * 8] = *(const uint4*)&A [(size_t)(rowbase + r) * K + k0 + c * 8];
            *(uint4*)&Bs[idx * 8] = *(const uint4*)&Bt[(size_t)(colbase + r) * K + k0 + c * 8];
        }
        __syncthreads();
        bf16x8 aF[4], bF[4];
#pragma unroll
        for (int m = 0; m < 4; m++) aF[m] = *(const bf16x8*)&As[(wr * 64 + m * 16 + lrow) * 32 + lk];
#pragma unroll
        for (int n = 0; n < 4; n++) bF[n] = *(const bf16x8*)&Bs[(wc * 64 + n * 16 + lrow) * 32 + lk];
#pragma unroll
        for (int m = 0; m < 4; m++)
#pragma unroll
            for (int n = 0; n < 4; n++)
                acc[m][n] = __builtin_amdgcn_mfma_f32_16x16x32_bf16(aF[m], bF[n], acc[m][n], 0, 0, 0);
        __syncthreads();
    }

#pragma unroll
    for (int m = 0; m < 4; m++) {
        int row = rowbase + wr * 64 + m * 16 + (lane >> 4) * 4;
#pragma unroll
        for (int n = 0; n < 4; n++) {
            int col = colbase + wc * 64 + n * 16 + (lane & 15);
            float bv = bias ? bias[col] : 0.0f;
#pragma unroll
            for (int r = 0; r < 4; r++) {
                float x = acc[m][n][r] + bv;
                if (GELU) x = gelu_exact(x);
                if (OUTBF) Cb[(size_t)(row + r) * M + col] = (__bf16)x;
                else       C [(size_t)(row + r) * M + col] = x;
            }
        }
    }
}

// ---------------------------------------------------------------- fused attention
// grid: B_*H_ blocks, 256 threads (thread = query row). QKV bf16 [N][1536].
__global__ __launch_bounds__(256) void k_attn(const __bf16* __restrict__ QKV,
                                              const uint8_t* __restrict__ ebt,
                                              const unsigned char* __restrict__ mc,
                                              __bf16* __restrict__ T) {
    __shared__ __align__(16) float Ks[64][64];
    __shared__ __align__(16) float Vs[64][64];
    __shared__ __align__(16) uint8_t Bs[256][68];
    int bh = blockIdx.x;
    int b = bh >> 3, h = bh & 7;
    int i = threadIdx.x;
    const uint8_t* plane = ebt + ((size_t)bh << 16);

    float q[64];
    {
        const __bf16* qp = &QKV[((size_t)((b << 8) + i)) * 1536 + h * 64];
#pragma unroll
        for (int c = 0; c < 8; c++) {
            bf16x8 v = *(const bf16x8*)(qp + c * 8);
#pragma unroll
            for (int e = 0; e < 8; e++) q[c * 8 + e] = (float)v[e];
        }
    }
    float m = -INFINITY, l = 0.0f;
    float o[64] = {};

    for (int t0 = 0; t0 < SP; t0 += 64) {
        __syncthreads();
#pragma unroll
        for (int p = 0; p < 2; p++) {
            int seg = i + p * 256;                 // 512 segs: 64 rows x 8
            int r = seg >> 3, c = seg & 7;
            size_t base = ((size_t)((b << 8) + t0 + r)) * 1536 + h * 64 + c * 8;
            bf16x8 kv = *(const bf16x8*)&QKV[512 + base];
            bf16x8 vv = *(const bf16x8*)&QKV[1024 + base];
#pragma unroll
            for (int e = 0; e < 8; e++) {
                Ks[r][c * 8 + e] = (float)kv[e];
                Vs[r][c * 8 + e] = (float)vv[e];
            }
        }
#pragma unroll
        for (int p = 0; p < 4; p++) {
            int seg = i + p * 256;                 // 1024 segs of 16B: 256 rows x 4
            int r = seg >> 2, c = seg & 3;
            uint4 u = *(const uint4*)&plane[(size_t)r * 256 + t0 + c * 16];
            uint32_t* dst = (uint32_t*)&Bs[r][c * 16];
            dst[0] = u.x; dst[1] = u.y; dst[2] = u.z; dst[3] = u.w;
        }
        __syncthreads();
        for (int j = 0; j < 64; j++) {
            int jj = t0 + j;
            if (mc[(b << 8) + jj]) continue;       // wave-uniform skip
            float dot = 0.0f;
#pragma unroll
            for (int d4 = 0; d4 < 16; d4++) {
                float4 kv = *(const float4*)&Ks[j][d4 * 4];
                dot = fmaf(q[d4*4], kv.x, dot);
                dot = fmaf(q[d4*4+1], kv.y, dot);
                dot = fmaf(q[d4*4+2], kv.z, dot);
                dot = fmaf(q[d4*4+3], kv.w, dot);
            }
            float s = dot * 0.125f + dec_e4m3(Bs[i][j]);
            float mnew = fmaxf(m, s);
            float corr = __expf(m - mnew);
            float p = __expf(s - mnew);
            l = l * corr + p;
#pragma unroll
            for (int d4 = 0; d4 < 16; d4++) {
                float4 vv = *(const float4*)&Vs[j][d4 * 4];
                o[d4*4]   = o[d4*4]  * corr + p * vv.x;
                o[d4*4+1] = o[d4*4+1]* corr + p * vv.y;
                o[d4*4+2] = o[d4*4+2]* corr + p * vv.z;
                o[d4*4+3] = o[d4*4+3]* corr + p * vv.w;
            }
            m = mnew;
        }
    }
    float inv = 1.0f / l;
    __bf16* op = &T[((size_t)((b << 8) + i)) * 512 + h * 64];
#pragma unroll
    for (int c = 0; c < 8; c++) {
        bf16x8 v;
#pragma unroll
        for (int e = 0; e < 8; e++) v[e] = (__bf16)(o[c * 8 + e] * inv);
        *(bf16x8*)(op + c * 8) = v;
    }
}

// ---------------------------------------------------------------- residual + LayerNorm (f32 + bf16 out)
__global__ __launch_bounds__(256) void k_ln(float* __restrict__ X, __bf16* __restrict__ Xb,
                                            const float* __restrict__ U,
                                            const float* __restrict__ g,
                                            const float* __restrict__ bb) {
    __shared__ float red[4];
    int row = blockIdx.x, t = threadIdx.x;
    size_t base = (size_t)row * D_;
    float v0 = X[base + t] + U[base + t];
    float v1 = X[base + t + 256] + U[base + t + 256];
    float s = wave_sum(v0 + v1);
    if ((t & 63) == 0) red[t >> 6] = s;
    __syncthreads();
    float mean = (red[0] + red[1] + red[2] + red[3]) * (1.0f / D_);
    float d0 = v0 - mean, d1 = v1 - mean;
    float s2 = wave_sum(d0 * d0 + d1 * d1);
    __syncthreads();
    if ((t & 63) == 0) red[t >> 6] = s2;
    __syncthreads();
    float var = (red[0] + red[1] + red[2] + red[3]) * (1.0f / D_);
    float rr = rsqrtf(var + EPS);
    float o0 = d0 * rr * g[t] + bb[t];
    float o1 = d1 * rr * g[t + 256] + bb[t + 256];
    X[base + t]        = o0;
    X[base + t + 256]  = o1;
    Xb[base + t]       = (__bf16)o0;
    Xb[base + t + 256] = (__bf16)o1;
}

// ---------------------------------------------------------------- MLP head on CLS
__global__ __launch_bounds__(256) void k_head(const float* __restrict__ X,
                                              const float* __restrict__ W1,
                                              const float* __restrict__ b1,
                                              const float* __restrict__ W2,
                                              const float* __restrict__ b2,
                                              float* __restrict__ out) {
    __shared__ float cls[D_];
    __shared__ float red[4];
    int b = blockIdx.x, t = threadIdx.x;
    size_t base = (size_t)(b << 8) * D_;
    cls[t]       = X[base + t];
    cls[t + 256] = X[base + t + 256];
    __syncthreads();
    float acc = 0.0f;
    for (int d = 0; d < D_; d++) acc = fmaf(cls[d], W1[(size_t)d * HID_ + t], acc);
    acc += b1[t];
    float hsum = wave_sum(gelu_exact(acc) * W2[t]);
    if ((t & 63) == 0) red[t >> 6] = hsum;
    __syncthreads();
    if (t == 0) out[b] = red[0] + red[1] + red[2] + red[3] + b2[0];
}

// ---------------------------------------------------------------- launch
extern "C" void kernel_launch(void* const* d_in, const int* in_sizes, int n_in,
                              void* d_out, int out_size, void* d_ws, size_t ws_size,
                              hipStream_t stream) {
    const float* atom = (const float*)d_in[0];
    const float* eb   = (const float*)d_in[1];
    const void*  mraw = d_in[2];
    const float* cls  = (const float*)d_in[3];
    const float* Wq = (const float*)d_in[4];  const float* bq = (const float*)d_in[5];
    const float* Wk = (const float*)d_in[6];  const float* bk = (const float*)d_in[7];
    const float* Wv = (const float*)d_in[8];  const float* bv = (const float*)d_in[9];
    const float* Wo = (const float*)d_in[10]; const float* bo = (const float*)d_in[11];
    const float* g1 = (const float*)d_in[12]; const float* be1 = (const float*)d_in[13];
    const float* W1 = (const float*)d_in[14]; const float* b1 = (const float*)d_in[15];
    const float* W2 = (const float*)d_in[16]; const float* b2 = (const float*)d_in[17];
    const float* g2 = (const float*)d_in[18]; const float* be2 = (const float*)d_in[19];
    const float* hW1 = (const float*)d_in[20]; const float* hb1 = (const float*)d_in[21];
    const float* hW2 = (const float*)d_in[22]; const float* hb2 = (const float*)d_in[23];
    float* out = (float*)d_out;

    // ---- workspace layout (bytes) ----
    char* p = (char*)d_ws;
    float*  X     = (float*)p;                 p += (size_t)N_ * D_ * 4;        // 33.55 MB
    float*  Ub    = (float*)p;                 p += (size_t)N_ * D_ * 4;        // 33.55 MB
    __bf16* Xb    = (__bf16*)p;                p += (size_t)N_ * D_ * 2;        // 16.78 MB
    char*   R     = p;                         p += (size_t)N_ * FF_ * 2;       // 67.11 MB
    __bf16* QKVb  = (__bf16*)R;                                                 // [N][1536]
    __bf16* Tb    = (__bf16*)(R + (size_t)N_ * 1536 * 2);                       // [N][512]
    __bf16* Hb    = (__bf16*)R;                                                 // [N][2048]
    uint8_t* ebt  = (uint8_t*)p;               p += (size_t)B_ * H_ * SP * SP;  // 33.55 MB
    __bf16* Wqkvt = (__bf16*)p;                p += (size_t)L_ * 1536 * 512 * 2;
    __bf16* Wot   = (__bf16*)p;                p += (size_t)L_ * 512 * 512 * 2;
    __bf16* W1t   = (__bf16*)p;                p += (size_t)L_ * 2048 * 512 * 2;
    __bf16* W2t   = (__bf16*)p;                p += (size_t)L_ * 512 * 2048 * 2;
    float*  bqkv  = (float*)p;                 p += (size_t)L_ * 1536 * 4;
    unsigned char* mc = (unsigned char*)p;     p += B_ * SP;
    int* flag = (int*)p;

    // ---- prep (every call; deterministic) ----
    hipMemsetAsync(flag, 0, 4, stream);
    k_mask_detect<<<16, 256, 0, stream>>>((const unsigned int*)mraw, (B_ * S_) / 4, flag);
    k_mask_prep<<<(B_ * SP) / 256, 256, 0, stream>>>(mraw, flag, mc);
    k_bcat<<<(L_ * 1536) / 256, 256, 0, stream>>>(bq, bk, bv, bqkv);
    // weight transpose+cast: K=512 rows x M cols -> [M][K]
    k_wt<<<dim3(8, 8, L_),  256, 0, stream>>>(Wq, Wqkvt, 512, 512, 0,    262144, 786432);
    k_wt<<<dim3(8, 8, L_),  256, 0, stream>>>(Wk, Wqkvt, 512, 512, 512,  262144, 786432);
    k_wt<<<dim3(8, 8, L_),  256, 0, stream>>>(Wv, Wqkvt, 512, 512, 1024, 262144, 786432);
    k_wt<<<dim3(8, 8, L_),  256, 0, stream>>>(Wo, Wot,   512, 512, 0,    262144, 262144);
    k_wt<<<dim3(32, 8, L_), 256, 0, stream>>>(W1, W1t,   512, 2048, 0,   1048576, 1048576);
    k_wt<<<dim3(8, 32, L_), 256, 0, stream>>>(W2, W2t,   2048, 512, 0,   1048576, 1048576);
    k_ebt<<<B_ * SP, 256, 0, stream>>>(eb, ebt);
    k_build_x<<<(N_ * D_) / 256, 256, 0, stream>>>(atom, cls, X, Xb);

    dim3 gQKV(12, 128), gD(4, 128), gF1(16, 128);
    for (int l = 0; l < L_; l++) {
        k_gemm<1, 0><<<gQKV, 256, 0, stream>>>(Xb, Wqkvt + (size_t)l * 786432, bqkv + l * 1536,
                                               nullptr, QKVb, 512, 1536);
        k_attn<<<B_ * H_, 256, 0, stream>>>(QKVb, ebt, mc, Tb);
        k_gemm<0, 0><<<gD, 256, 0, stream>>>(Tb, Wot + (size_t)l * 262144, bo + l * 512,
                                             Ub, nullptr, 512, 512);
        k_ln<<<N_, 256, 0, stream>>>(X, Xb, Ub, g1 + l * D_, be1 + l * D_);
        k_gemm<1, 1><<<gF1, 256, 0, stream>>>(Xb, W1t + (size_t)l * 1048576, b1 + l * FF_,
                                              nullptr, Hb, 512, 2048);
        k_gemm<0, 0><<<gD, 256, 0, stream>>>(Hb, W2t + (size_t)l * 1048576, b2 + l * D_,
                                             Ub, nullptr, 2048, 512);
        k_ln<<<N_, 256, 0, stream>>>(X, Xb, Ub, g2 + l * D_, be2 + l * D_);
    }
    k_head<<<B_, 256, 0, stream>>>(X, hW1, hb1, hW2, hb2, out);
}

// Round 3
// 2302.080 us; speedup vs baseline: 5.2165x; 1.2545x over previous
//
#include <hip/hip_runtime.h>
#include <math.h>
#include <stdint.h>

#define B_   64
#define S_   255
#define SP   256
#define D_   512
#define H_   8
#define L_   6
#define FF_  2048
#define HID_ 256
#define N_   (B_*SP)       // 16384 rows
#define EPS  1e-5f

using bf16x8 = __bf16 __attribute__((ext_vector_type(8)));
using f32x4  = float __attribute__((ext_vector_type(4)));

// ---------------------------------------------------------------- utilities
__device__ inline float wave_sum(float v) {
#pragma unroll
    for (int off = 32; off; off >>= 1) v += __shfl_xor(v, off);
    return v;
}

__device__ inline float gelu_exact(float x) {
    return 0.5f * x * (1.0f + erff(x * 0.70710678118654752f));
}

// fp8 e4m3fn encode (RNE) / decode
__device__ inline uint8_t enc_e4m3(float f) {
    uint32_t u = __float_as_uint(f);
    uint32_t s = (u >> 24) & 0x80u;
    float a = fabsf(f);
    if (a < 0.015625f) {                       // denormal range: multiples of 2^-9
        int m = (int)rintf(a * 512.0f);
        if (m >= 8) return (uint8_t)(s | 0x08);
        return (uint8_t)(s | (uint32_t)m);
    }
    if (a > 448.0f) return (uint8_t)(s | 0x7E);
    uint32_t b = __float_as_uint(a);
    uint32_t expf_ = b >> 23;                  // >= 121 here
    uint32_t mant = b & 0x7FFFFF;
    uint32_t keep = mant >> 20;
    uint32_t rest = mant & 0xFFFFF;
    if (rest > 0x80000u || (rest == 0x80000u && (keep & 1))) keep++;
    if (keep == 8) { keep = 0; expf_++; }
    int e8 = (int)expf_ - 120;
    if (e8 >= 16) return (uint8_t)(s | 0x7E);
    return (uint8_t)(s | ((uint32_t)e8 << 3) | keep);
}

__device__ inline float dec_e4m3(uint32_t b) {
    uint32_t mag = b & 0x7Fu;
    float fm = __uint_as_float((mag << 20) + (120u << 23));
    if ((mag >> 3) == 0) fm = fm * 2.0f - 0.015625f;   // denormal fix
    return (b & 0x80u) ? -fm : fm;
}

// ---------------------------------------------------------------- build X = [cls; atom]
__global__ void k_build_x(const float* __restrict__ atom, const float* __restrict__ cls,
                          float* __restrict__ X, __bf16* __restrict__ Xb) {
    int idx = blockIdx.x * 256 + threadIdx.x;      // over N_*D_
    int col = idx & (D_ - 1);
    int row = idx >> 9;
    int sr  = row & (SP - 1);
    int b   = row >> 8;
    float v = (sr == 0) ? cls[col] : atom[((size_t)(b * S_) + (sr - 1)) * D_ + col];
    X[idx]  = v;
    Xb[idx] = (__bf16)v;
}

// ---------------------------------------------------------------- mask layout detection
__global__ void k_mask_detect(const unsigned int* __restrict__ mw, int nw, int* flag) {
    int i = blockIdx.x * 256 + threadIdx.x;
    if (i < nw && mw[i] > 1u) atomicOr(flag, 1);
}

// mask -> additive f32 table: 0 (keep) or -1e30 (masked). CLS (j==0) never masked.
__global__ void k_mask_prep(const void* __restrict__ mraw, const int* __restrict__ flag,
                            float* __restrict__ mskadd) {
    int i = blockIdx.x * 256 + threadIdx.x;        // over B_*SP
    int b = i >> 8, j = i & 255;
    float v = 0.0f;
    if (j > 0) {
        int src = b * S_ + (j - 1);
        bool m = (*flag) ? (((const unsigned char*)mraw)[src] != 0)
                         : (((const int*)mraw)[src] != 0);
        if (m) v = -1e30f;
    }
    mskadd[i] = v;
}

// ---------------------------------------------------------------- weight transpose+cast
__global__ __launch_bounds__(256) void k_wt(const float* __restrict__ W, __bf16* __restrict__ Wt,
                                            int K, int Mw, int mout_off,
                                            size_t in_lstride, size_t out_lstride) {
    __shared__ float T[64][65];
    int l = blockIdx.z;
    int m0 = blockIdx.x * 64, k0 = blockIdx.y * 64;
    const float* Wl = W + (size_t)l * in_lstride;
    __bf16* Wtl = Wt + (size_t)l * out_lstride;
    int tid = threadIdx.x;
    int cc = tid & 63, rr = tid >> 6;
#pragma unroll
    for (int p = 0; p < 16; p++) {
        int kk = rr + p * 4;
        T[kk][cc] = Wl[(size_t)(k0 + kk) * Mw + m0 + cc];
    }
    __syncthreads();
#pragma unroll
    for (int p = 0; p < 16; p++) {
        int mm = rr + p * 4;
        Wtl[(size_t)(mout_off + m0 + mm) * K + k0 + cc] = (__bf16)T[cc][mm];
    }
}

// ---------------------------------------------------------------- qkv bias concat
__global__ void k_bcat(const float* __restrict__ bq, const float* __restrict__ bk,
                       const float* __restrict__ bv, float* __restrict__ bqkv) {
    int i = blockIdx.x * 256 + threadIdx.x;        // over 6*1536
    int l = i / 1536, c = i % 1536;
    float v;
    if (c < 512)       v = bq[l * 512 + c];
    else if (c < 1024) v = bk[l * 512 + c - 512];
    else               v = bv[l * 512 + c - 1024];
    bqkv[i] = v;
}

// ---------------------------------------------------------------- bias repack: eb -> fp8 in MFMA fragment layout
// dword index x = ((((b*8+h)*4 + t)*4 + w)*4 + mq)*256 + c*16 + g*4 + r ; byte nk within dword.
// element: q = w*64+mq*16+g*4+r ; k = t*64+nk*16+c
__global__ __launch_bounds__(256) void k_ebt3(const float* __restrict__ eb, uint8_t* __restrict__ ebt) {
    int x = blockIdx.x * 256 + threadIdx.x;        // 8388608 dwords
    int r  = x & 3;
    int gg = (x >> 2) & 3;
    int cc = (x >> 4) & 15;
    int mq = (x >> 8) & 3;
    int w  = (x >> 10) & 3;
    int t  = (x >> 12) & 3;
    int h  = (x >> 14) & 7;
    int b  = x >> 17;
    int q = w * 64 + mq * 16 + gg * 4 + r;
    uint32_t out = 0;
    if (q > 0) {
#pragma unroll
        for (int nk = 0; nk < 4; nk++) {
            int k = t * 64 + nk * 16 + cc;
            if (k > 0) {
                float f = eb[(((size_t)(b * 255) + (q - 1)) * 255 + (k - 1)) * 8 + h];
                out |= (uint32_t)enc_e4m3(f) << (nk * 8);
            }
        }
    }
    ((uint32_t*)ebt)[x] = out;
}

// ---------------------------------------------------------------- V transpose per (b,h): Vt[bh][64 d][256 s]
__global__ __launch_bounds__(256) void k_vt(const __bf16* __restrict__ QKV, __bf16* __restrict__ Vt) {
    int bh = blockIdx.x, b = bh >> 3, h = bh & 7;
    int t = threadIdx.x;
    int d = t >> 2, sq = (t & 3) * 64;
    const __bf16* src = QKV + 1024 + h * 64 + d;
#pragma unroll
    for (int i = 0; i < 8; i++) {
        int s0 = sq + i * 8;
        bf16x8 v;
#pragma unroll
        for (int j = 0; j < 8; j++)
            v[j] = src[(size_t)((b << 8) + s0 + j) * 1536];
        *(bf16x8*)&Vt[((size_t)bh * 64 + d) * 256 + s0] = v;
    }
}

// ---------------------------------------------------------------- bf16 MFMA GEMM (unchanged)
template<int OUTBF, int GELU>
__global__ __launch_bounds__(256) void k_gemm(const __bf16* __restrict__ A,
                                              const __bf16* __restrict__ Bt,
                                              const float* __restrict__ bias,
                                              float* __restrict__ C,
                                              __bf16* __restrict__ Cb,
                                              int K, int M) {
    __shared__ __align__(16) __bf16 As[128 * 32];
    __shared__ __align__(16) __bf16 Bs[128 * 32];
    const int tid = threadIdx.x;
    const int wid = tid >> 6, lane = tid & 63;
    const int rowbase = blockIdx.y * 128, colbase = blockIdx.x * 128;
    const int wr = wid >> 1, wc = wid & 1;
    const int lrow = lane & 15, lk = (lane >> 4) * 8;

    f32x4 acc[4][4];
#pragma unroll
    for (int m = 0; m < 4; m++)
#pragma unroll
        for (int n = 0; n < 4; n++) acc[m][n] = f32x4{0.f, 0.f, 0.f, 0.f};

    for (int k0 = 0; k0 < K; k0 += 32) {
#pragma unroll
        for (int p = 0; p < 2; p++) {
            int idx = tid + p * 256;
            int r = idx >> 2, c = idx & 3;
            *(uint4*)&As[idx * 8] = *(const uint4*)&A [(size_t)(rowbase + r) * K + k0 + c * 8];
            *(uint4*)&Bs[idx * 8] = *(const uint4*)&Bt[(size_t)(colbase + r) * K + k0 + c * 8];
        }
        __syncthreads();
        bf16x8 aF[4], bF[4];
#pragma unroll
        for (int m = 0; m < 4; m++) aF[m] = *(const bf16x8*)&As[(wr * 64 + m * 16 + lrow) * 32 + lk];
#pragma unroll
        for (int n = 0; n < 4; n++) bF[n] = *(const bf16x8*)&Bs[(wc * 64 + n * 16 + lrow) * 32 + lk];
#pragma unroll
        for (int m = 0; m < 4; m++)
#pragma unroll
            for (int n = 0; n < 4; n++)
                acc[m][n] = __builtin_amdgcn_mfma_f32_16x16x32_bf16(aF[m], bF[n], acc[m][n], 0, 0, 0);
        __syncthreads();
    }

#pragma unroll
    for (int m = 0; m < 4; m++) {
        int row = rowbase + wr * 64 + m * 16 + (lane >> 4) * 4;
#pragma unroll
        for (int n = 0; n < 4; n++) {
            int col = colbase + wc * 64 + n * 16 + (lane & 15);
            float bv = bias ? bias[col] : 0.0f;
#pragma unroll
            for (int r = 0; r < 4; r++) {
                float x = acc[m][n][r] + bv;
                if (GELU) x = gelu_exact(x);
                if (OUTBF) Cb[(size_t)(row + r) * M + col] = (__bf16)x;
                else       C [(size_t)(row + r) * M + col] = x;
            }
        }
    }
}

// ---------------------------------------------------------------- MFMA fused attention
// grid: B_*H_ blocks, 256 threads = 4 waves; wave w owns q rows [w*64, w*64+64).
// Ks: K tile [64 key][64 d], Vs: V^T tile [64 d][64 key], both XOR-swizzled.
// Ps: per-wave P tile [64 q][64 key] bf16, XOR-swizzled.
__global__ __launch_bounds__(256, 2) void k_attn(const __bf16* __restrict__ QKV,
                                                 const uint8_t* __restrict__ ebt,
                                                 const float* __restrict__ mskadd,
                                                 const __bf16* __restrict__ Vt,
                                                 __bf16* __restrict__ T) {
    __shared__ __align__(16) char Ks[8192];
    __shared__ __align__(16) char Vs[8192];
    __shared__ __align__(16) char Ps[4][8192];
    __shared__ float Ma[256];
    const int bh = blockIdx.x, b = bh >> 3, h = bh & 7;
    const int tid = threadIdx.x, w = tid >> 6, lane = tid & 63;
    const int g = lane >> 4, c = lane & 15;

    Ma[tid] = mskadd[(b << 8) + tid];

    // Q fragments (registers): A-operand, lane holds Q[q=c][d=g*8.. (+32*ks)]
    bf16x8 qf[4][2];
#pragma unroll
    for (int mq = 0; mq < 4; mq++) {
        const __bf16* qrow = QKV + (size_t)((b << 8) + w * 64 + mq * 16 + c) * 1536 + h * 64;
#pragma unroll
        for (int ks = 0; ks < 2; ks++)
            qf[mq][ks] = *(const bf16x8*)(qrow + ks * 32 + g * 8);
    }

    f32x4 oacc[4][4];
    float m_s[4][4], l_s[4][4];
#pragma unroll
    for (int mq = 0; mq < 4; mq++)
#pragma unroll
        for (int r = 0; r < 4; r++) { m_s[mq][r] = -1e30f; l_s[mq][r] = 0.0f; }
#pragma unroll
    for (int mq = 0; mq < 4; mq++)
#pragma unroll
        for (int nd = 0; nd < 4; nd++) oacc[mq][nd] = f32x4{0.f, 0.f, 0.f, 0.f};

    for (int t = 0; t < 4; t++) {
        const int t0 = t * 64;
        __syncthreads();                          // prior tile's LDS reads done
#pragma unroll
        for (int p = 0; p < 2; p++) {
            int idx = tid + p * 256;
            int row = idx >> 3, c8 = idx & 7;
            int lds = row * 128 + ((c8 * 16) ^ ((row & 7) << 4));
            *(uint4*)(Ks + lds) = *(const uint4*)&QKV[(size_t)((b << 8) + t0 + row) * 1536 + 512 + h * 64 + c8 * 8];
            *(uint4*)(Vs + lds) = *(const uint4*)&Vt[((size_t)bh * 64 + row) * 256 + t0 + c8 * 8];
        }
        __syncthreads();

        // K fragments (B-operand, lane holds K[key=c(+nk*16)][d-slice]) and
        // V^T fragments (B-operand, lane holds V[k-slice][d=c(+nd*16)])
        bf16x8 kf[4][2], vb[4][2];
#pragma unroll
        for (int n = 0; n < 4; n++) {
            int row = n * 16 + c;
#pragma unroll
            for (int ks = 0; ks < 2; ks++) {
                int col = (g * 16 + ks * 64) ^ ((row & 7) << 4);
                kf[n][ks] = *(const bf16x8*)(Ks + row * 128 + col);
                vb[n][ks] = *(const bf16x8*)(Vs + row * 128 + col);
            }
        }

        const uint8_t* ebbase = ebt + ((((size_t)bh * 4 + t) * 4 + w) * 4) * 1024 + c * 64 + g * 16;
        char* psw = Ps[w];

#pragma unroll
        for (int mq = 0; mq < 4; mq++) {
            f32x4 sa[4];
#pragma unroll
            for (int nk = 0; nk < 4; nk++) sa[nk] = f32x4{0.f, 0.f, 0.f, 0.f};
#pragma unroll
            for (int ks = 0; ks < 2; ks++)
#pragma unroll
                for (int nk = 0; nk < 4; nk++)
                    sa[nk] = __builtin_amdgcn_mfma_f32_16x16x32_bf16(qf[mq][ks], kf[nk][ks], sa[nk], 0, 0, 0);

            uint4 b4 = *(const uint4*)(ebbase + mq * 1024);
            uint32_t bw0 = b4.x, bw1 = b4.y, bw2 = b4.z, bw3 = b4.w;
            float s[4][4];                         // [nk][r]
#pragma unroll
            for (int nk = 0; nk < 4; nk++) {
                s[nk][0] = sa[nk][0] * 0.125f + dec_e4m3((bw0 >> (nk * 8)) & 0xFF) + Ma[t0 + nk * 16 + c];
                s[nk][1] = sa[nk][1] * 0.125f + dec_e4m3((bw1 >> (nk * 8)) & 0xFF) + Ma[t0 + nk * 16 + c];
                s[nk][2] = sa[nk][2] * 0.125f + dec_e4m3((bw2 >> (nk * 8)) & 0xFF) + Ma[t0 + nk * 16 + c];
                s[nk][3] = sa[nk][3] * 0.125f + dec_e4m3((bw3 >> (nk * 8)) & 0xFF) + Ma[t0 + nk * 16 + c];
            }

            float corr[4];
#pragma unroll
            for (int r = 0; r < 4; r++) {
                float tm = fmaxf(fmaxf(s[0][r], s[1][r]), fmaxf(s[2][r], s[3][r]));
#pragma unroll
                for (int off = 1; off < 16; off <<= 1)
                    tm = fmaxf(tm, __shfl_xor(tm, off));
                float mnew = fmaxf(m_s[mq][r], tm);
                corr[r] = __expf(m_s[mq][r] - mnew);
                m_s[mq][r] = mnew;
                float psum = 0.0f;
#pragma unroll
                for (int nk = 0; nk < 4; nk++) {
                    s[nk][r] = __expf(s[nk][r] - mnew);
                    psum += s[nk][r];
                }
#pragma unroll
                for (int off = 1; off < 16; off <<= 1)
                    psum += __shfl_xor(psum, off);
                l_s[mq][r] = l_s[mq][r] * corr[r] + psum;
            }
#pragma unroll
            for (int nd = 0; nd < 4; nd++)
#pragma unroll
                for (int r = 0; r < 4; r++)
                    oacc[mq][nd][r] *= corr[r];

            // P -> per-wave LDS (bf16, swizzled), then read back as A-fragments
#pragma unroll
            for (int r = 0; r < 4; r++) {
                int qs = mq * 16 + g * 4 + r;
#pragma unroll
                for (int nk = 0; nk < 4; nk++)
                    *(__bf16*)(psw + qs * 128 + ((nk * 32 + c * 2) ^ ((qs & 7) << 4))) = (__bf16)s[nk][r];
            }
            bf16x8 pa[2];
            {
                int qs = mq * 16 + c;
#pragma unroll
                for (int ks = 0; ks < 2; ks++)
                    pa[ks] = *(const bf16x8*)(psw + qs * 128 + ((g * 16 + ks * 64) ^ ((qs & 7) << 4)));
            }
#pragma unroll
            for (int nd = 0; nd < 4; nd++)
#pragma unroll
                for (int ks = 0; ks < 2; ks++)
                    oacc[mq][nd] = __builtin_amdgcn_mfma_f32_16x16x32_bf16(pa[ks], vb[nd][ks], oacc[mq][nd], 0, 0, 0);
        }
    }

    // epilogue: O / l -> T (bf16)
#pragma unroll
    for (int mq = 0; mq < 4; mq++) {
#pragma unroll
        for (int r = 0; r < 4; r++) {
            float inv = 1.0f / l_s[mq][r];
            size_t rowb = (size_t)((b << 8) + w * 64 + mq * 16 + g * 4 + r) * 512 + h * 64 + c;
#pragma unroll
            for (int nd = 0; nd < 4; nd++)
                T[rowb + nd * 16] = (__bf16)(oacc[mq][nd][r] * inv);
        }
    }
}

// ---------------------------------------------------------------- residual + LayerNorm (f32 + bf16 out)
__global__ __launch_bounds__(256) void k_ln(float* __restrict__ X, __bf16* __restrict__ Xb,
                                            const float* __restrict__ U,
                                            const float* __restrict__ g,
                                            const float* __restrict__ bb) {
    __shared__ float red[4];
    int row = blockIdx.x, t = threadIdx.x;
    size_t base = (size_t)row * D_;
    float v0 = X[base + t] + U[base + t];
    float v1 = X[base + t + 256] + U[base + t + 256];
    float s = wave_sum(v0 + v1);
    if ((t & 63) == 0) red[t >> 6] = s;
    __syncthreads();
    float mean = (red[0] + red[1] + red[2] + red[3]) * (1.0f / D_);
    float d0 = v0 - mean, d1 = v1 - mean;
    float s2 = wave_sum(d0 * d0 + d1 * d1);
    __syncthreads();
    if ((t & 63) == 0) red[t >> 6] = s2;
    __syncthreads();
    float var = (red[0] + red[1] + red[2] + red[3]) * (1.0f / D_);
    float rr = rsqrtf(var + EPS);
    float o0 = d0 * rr * g[t] + bb[t];
    float o1 = d1 * rr * g[t + 256] + bb[t + 256];
    X[base + t]        = o0;
    X[base + t + 256]  = o1;
    Xb[base + t]       = (__bf16)o0;
    Xb[base + t + 256] = (__bf16)o1;
}

// ---------------------------------------------------------------- MLP head on CLS
__global__ __launch_bounds__(256) void k_head(const float* __restrict__ X,
                                              const float* __restrict__ W1,
                                              const float* __restrict__ b1,
                                              const float* __restrict__ W2,
                                              const float* __restrict__ b2,
                                              float* __restrict__ out) {
    __shared__ float cls[D_];
    __shared__ float red[4];
    int b = blockIdx.x, t = threadIdx.x;
    size_t base = (size_t)(b << 8) * D_;
    cls[t]       = X[base + t];
    cls[t + 256] = X[base + t + 256];
    __syncthreads();
    float acc = 0.0f;
    for (int d = 0; d < D_; d++) acc = fmaf(cls[d], W1[(size_t)d * HID_ + t], acc);
    acc += b1[t];
    float hsum = wave_sum(gelu_exact(acc) * W2[t]);
    if ((t & 63) == 0) red[t >> 6] = hsum;
    __syncthreads();
    if (t == 0) out[b] = red[0] + red[1] + red[2] + red[3] + b2[0];
}

// ---------------------------------------------------------------- launch
extern "C" void kernel_launch(void* const* d_in, const int* in_sizes, int n_in,
                              void* d_out, int out_size, void* d_ws, size_t ws_size,
                              hipStream_t stream) {
    const float* atom = (const float*)d_in[0];
    const float* eb   = (const float*)d_in[1];
    const void*  mraw = d_in[2];
    const float* cls  = (const float*)d_in[3];
    const float* Wq = (const float*)d_in[4];  const float* bq = (const float*)d_in[5];
    const float* Wk = (const float*)d_in[6];  const float* bk = (const float*)d_in[7];
    const float* Wv = (const float*)d_in[8];  const float* bv = (const float*)d_in[9];
    const float* Wo = (const float*)d_in[10]; const float* bo = (const float*)d_in[11];
    const float* g1 = (const float*)d_in[12]; const float* be1 = (const float*)d_in[13];
    const float* W1 = (const float*)d_in[14]; const float* b1 = (const float*)d_in[15];
    const float* W2 = (const float*)d_in[16]; const float* b2 = (const float*)d_in[17];
    const float* g2 = (const float*)d_in[18]; const float* be2 = (const float*)d_in[19];
    const float* hW1 = (const float*)d_in[20]; const float* hb1 = (const float*)d_in[21];
    const float* hW2 = (const float*)d_in[22]; const float* hb2 = (const float*)d_in[23];
    float* out = (float*)d_out;

    // ---- workspace layout ----
    char* p = (char*)d_ws;
    float*  X     = (float*)p;                 p += (size_t)N_ * D_ * 4;        // 33.55 MB
    float*  Ub    = (float*)p;                 p += (size_t)N_ * D_ * 4;        // 33.55 MB (also hosts Vt during attn)
    __bf16* Xb    = (__bf16*)p;                p += (size_t)N_ * D_ * 2;        // 16.78 MB
    char*   R     = p;                         p += (size_t)N_ * FF_ * 2;       // 67.11 MB
    __bf16* QKVb  = (__bf16*)R;                                                 // [N][1536]
    __bf16* Tb    = (__bf16*)(R + (size_t)N_ * 1536 * 2);                       // [N][512]
    __bf16* Hb    = (__bf16*)R;                                                 // [N][2048]
    uint8_t* ebt  = (uint8_t*)p;               p += (size_t)B_ * H_ * SP * SP;  // 33.55 MB (fragment layout)
    __bf16* Wqkvt = (__bf16*)p;                p += (size_t)L_ * 1536 * 512 * 2;
    __bf16* Wot   = (__bf16*)p;                p += (size_t)L_ * 512 * 512 * 2;
    __bf16* W1t   = (__bf16*)p;                p += (size_t)L_ * 2048 * 512 * 2;
    __bf16* W2t   = (__bf16*)p;                p += (size_t)L_ * 512 * 2048 * 2;
    float*  bqkv  = (float*)p;                 p += (size_t)L_ * 1536 * 4;
    float*  mskadd= (float*)p;                 p += (size_t)B_ * SP * 4;        // 64 KB
    int* flag = (int*)p;
    __bf16* Vt = (__bf16*)Ub;                  // V^T scratch, only live during attention

    // ---- prep (every call; deterministic) ----
    hipMemsetAsync(flag, 0, 4, stream);
    k_mask_detect<<<16, 256, 0, stream>>>((const unsigned int*)mraw, (B_ * S_) / 4, flag);
    k_mask_prep<<<(B_ * SP) / 256, 256, 0, stream>>>(mraw, flag, mskadd);
    k_bcat<<<(L_ * 1536) / 256, 256, 0, stream>>>(bq, bk, bv, bqkv);
    k_wt<<<dim3(8, 8, L_),  256, 0, stream>>>(Wq, Wqkvt, 512, 512, 0,    262144, 786432);
    k_wt<<<dim3(8, 8, L_),  256, 0, stream>>>(Wk, Wqkvt, 512, 512, 512,  262144, 786432);
    k_wt<<<dim3(8, 8, L_),  256, 0, stream>>>(Wv, Wqkvt, 512, 512, 1024, 262144, 786432);
    k_wt<<<dim3(8, 8, L_),  256, 0, stream>>>(Wo, Wot,   512, 512, 0,    262144, 262144);
    k_wt<<<dim3(32, 8, L_), 256, 0, stream>>>(W1, W1t,   512, 2048, 0,   1048576, 1048576);
    k_wt<<<dim3(8, 32, L_), 256, 0, stream>>>(W2, W2t,   2048, 512, 0,   1048576, 1048576);
    k_ebt3<<<32768, 256, 0, stream>>>(eb, ebt);
    k_build_x<<<(N_ * D_) / 256, 256, 0, stream>>>(atom, cls, X, Xb);

    dim3 gQKV(12, 128), gD(4, 128), gF1(16, 128);
    for (int l = 0; l < L_; l++) {
        k_gemm<1, 0><<<gQKV, 256, 0, stream>>>(Xb, Wqkvt + (size_t)l * 786432, bqkv + l * 1536,
                                               nullptr, QKVb, 512, 1536);
        k_vt<<<B_ * H_, 256, 0, stream>>>(QKVb, Vt);
        k_attn<<<B_ * H_, 256, 0, stream>>>(QKVb, ebt, mskadd, Vt, Tb);
        k_gemm<0, 0><<<gD, 256, 0, stream>>>(Tb, Wot + (size_t)l * 262144, bo + l * 512,
                                             Ub, nullptr, 512, 512);
        k_ln<<<N_, 256, 0, stream>>>(X, Xb, Ub, g1 + l * D_, be1 + l * D_);
        k_gemm<1, 1><<<gF1, 256, 0, stream>>>(Xb, W1t + (size_t)l * 1048576, b1 + l * FF_,
                                              nullptr, Hb, 512, 2048);
        k_gemm<0, 0><<<gD, 256, 0, stream>>>(Hb, W2t + (size_t)l * 1048576, b2 + l * D_,
                                             Ub, nullptr, 2048, 512);
        k_ln<<<N_, 256, 0, stream>>>(X, Xb, Ub, g2 + l * D_, be2 + l * D_);
    }
    k_head<<<B_, 256, 0, stream>>>(X, hW1, hb1, hW2, hb2, out);
}

// Round 4
// 2003.116 us; speedup vs baseline: 5.9950x; 1.1492x over previous
//
#include <hip/hip_runtime.h>
#include <math.h>
#include <stdint.h>

#define B_   64
#define S_   255
#define SP   256
#define D_   512
#define H_   8
#define L_   6
#define FF_  2048
#define HID_ 256
#define N_   (B_*SP)       // 16384 rows
#define EPS  1e-5f

using bf16x8 = __bf16 __attribute__((ext_vector_type(8)));
using f32x4  = float __attribute__((ext_vector_type(4)));
using u16x4  = unsigned short __attribute__((ext_vector_type(4)));

// ---------------------------------------------------------------- utilities
__device__ inline float wave_sum(float v) {
#pragma unroll
    for (int off = 32; off; off >>= 1) v += __shfl_xor(v, off);
    return v;
}

__device__ inline float gelu_exact(float x) {
    return 0.5f * x * (1.0f + erff(x * 0.70710678118654752f));
}

__device__ inline unsigned short bf_bits(float x) {
    __bf16 h = (__bf16)x;
    return *(unsigned short*)&h;
}

// fp8 e4m3fn encode (RNE) / decode
__device__ inline uint8_t enc_e4m3(float f) {
    uint32_t u = __float_as_uint(f);
    uint32_t s = (u >> 24) & 0x80u;
    float a = fabsf(f);
    if (a < 0.015625f) {
        int m = (int)rintf(a * 512.0f);
        if (m >= 8) return (uint8_t)(s | 0x08);
        return (uint8_t)(s | (uint32_t)m);
    }
    if (a > 448.0f) return (uint8_t)(s | 0x7E);
    uint32_t b = __float_as_uint(a);
    uint32_t expf_ = b >> 23;
    uint32_t mant = b & 0x7FFFFF;
    uint32_t keep = mant >> 20;
    uint32_t rest = mant & 0xFFFFF;
    if (rest > 0x80000u || (rest == 0x80000u && (keep & 1))) keep++;
    if (keep == 8) { keep = 0; expf_++; }
    int e8 = (int)expf_ - 120;
    if (e8 >= 16) return (uint8_t)(s | 0x7E);
    return (uint8_t)(s | ((uint32_t)e8 << 3) | keep);
}

__device__ inline float dec_e4m3(uint32_t b) {
    uint32_t mag = b & 0x7Fu;
    float fm = __uint_as_float((mag << 20) + (120u << 23));
    if ((mag >> 3) == 0) fm = fm * 2.0f - 0.015625f;
    return (b & 0x80u) ? -fm : fm;
}

// async global->LDS 16B (m97 recipe)
#define GLOAD16(gsrc, ldst) \
    __builtin_amdgcn_global_load_lds((const __attribute__((address_space(1))) unsigned int*)(gsrc), \
                                     (__attribute__((address_space(3))) unsigned int*)(ldst), 16, 0, 0)

// ---------------------------------------------------------------- build X = [cls; atom]
__global__ void k_build_x(const float* __restrict__ atom, const float* __restrict__ cls,
                          float* __restrict__ X, __bf16* __restrict__ Xb) {
    int idx = blockIdx.x * 256 + threadIdx.x;
    int col = idx & (D_ - 1);
    int row = idx >> 9;
    int sr  = row & (SP - 1);
    int b   = row >> 8;
    float v = (sr == 0) ? cls[col] : atom[((size_t)(b * S_) + (sr - 1)) * D_ + col];
    X[idx]  = v;
    Xb[idx] = (__bf16)v;
}

// ---------------------------------------------------------------- mask layout detection
__global__ void k_mask_detect(const unsigned int* __restrict__ mw, int nw, int* flag) {
    int i = blockIdx.x * 256 + threadIdx.x;
    if (i < nw && mw[i] > 1u) atomicOr(flag, 1);
}

__global__ void k_mask_prep(const void* __restrict__ mraw, const int* __restrict__ flag,
                            float* __restrict__ mskadd) {
    int i = blockIdx.x * 256 + threadIdx.x;
    int b = i >> 8, j = i & 255;
    float v = 0.0f;
    if (j > 0) {
        int src = b * S_ + (j - 1);
        bool m = (*flag) ? (((const unsigned char*)mraw)[src] != 0)
                         : (((const int*)mraw)[src] != 0);
        if (m) v = -1e30f;
    }
    mskadd[i] = v;
}

// ---------------------------------------------------------------- weight transpose+cast
__global__ __launch_bounds__(256) void k_wt(const float* __restrict__ W, __bf16* __restrict__ Wt,
                                            int K, int Mw, int mout_off,
                                            size_t in_lstride, size_t out_lstride) {
    __shared__ float T[64][65];
    int l = blockIdx.z;
    int m0 = blockIdx.x * 64, k0 = blockIdx.y * 64;
    const float* Wl = W + (size_t)l * in_lstride;
    __bf16* Wtl = Wt + (size_t)l * out_lstride;
    int tid = threadIdx.x;
    int cc = tid & 63, rr = tid >> 6;
#pragma unroll
    for (int p = 0; p < 16; p++) {
        int kk = rr + p * 4;
        T[kk][cc] = Wl[(size_t)(k0 + kk) * Mw + m0 + cc];
    }
    __syncthreads();
#pragma unroll
    for (int p = 0; p < 16; p++) {
        int mm = rr + p * 4;
        Wtl[(size_t)(mout_off + m0 + mm) * K + k0 + cc] = (__bf16)T[cc][mm];
    }
}

// ---------------------------------------------------------------- qkv bias concat
__global__ void k_bcat(const float* __restrict__ bq, const float* __restrict__ bk,
                       const float* __restrict__ bv, float* __restrict__ bqkv) {
    int i = blockIdx.x * 256 + threadIdx.x;
    int l = i / 1536, c = i % 1536;
    float v;
    if (c < 512)       v = bq[l * 512 + c];
    else if (c < 1024) v = bk[l * 512 + c - 512];
    else               v = bv[l * 512 + c - 1024];
    bqkv[i] = v;
}

// ---------------------------------------------------------------- bias repack (coalesced reads)
// block = (b, q); stage the contiguous eb row, emit fragment-layout fp8 dwords.
// dword index x = ((((b*8+h)*4 + t)*4 + w)*4 + mq)*256 + c*16 + g*4 + r
// with q = w*64 + mq*16 + g*4 + r ; dword byte nk -> key k = t*64 + nk*16 + c
__global__ __launch_bounds__(256) void k_ebt4(const float* __restrict__ eb, uint8_t* __restrict__ ebt) {
    __shared__ float Ls[255 * 9];                  // padded stride 9: conflict-free
    int blk = blockIdx.x;
    int b = blk >> 8, q = blk & 255;
    int t = threadIdx.x;
    if (q > 0) {
        const float* src = eb + ((size_t)(b * 255) + (q - 1)) * 2040;
        for (int p = 0; p < 8; p++) {
            int idx = t + p * 256;
            if (idx < 2040) Ls[(idx >> 3) * 9 + (idx & 7)] = src[idx];
        }
    }
    __syncthreads();
    int w = q >> 6, mq = (q >> 4) & 3, g = (q >> 2) & 3, r = q & 3;
    uint32_t* outp = (uint32_t*)ebt;
#pragma unroll
    for (int p = 0; p < 2; p++) {
        int slot = t + p * 256;                    // 512 = 8h x 4t x 16c
        int hh = slot >> 6, tl = (slot >> 4) & 3, cc = slot & 15;
        uint32_t d = 0;
        if (q > 0) {
#pragma unroll
            for (int nk = 0; nk < 4; nk++) {
                int k = tl * 64 + nk * 16 + cc;
                if (k > 0) d |= (uint32_t)enc_e4m3(Ls[(k - 1) * 9 + hh]) << (nk * 8);
            }
        }
        size_t x = ((((size_t)(b * 8 + hh) * 4 + tl) * 4 + w) * 4 + mq) * 256 + cc * 16 + g * 4 + r;
        outp[x] = d;
    }
}

// ---------------------------------------------------------------- bf16 MFMA GEMM
// A [N][K] bf16; Bt [M][K] bf16; 128x128 tile, 4 waves, BK=32, global_load_lds staging.
// vtout: if non-null, blocks with colbase>=1024 write V^T [bh][64 d][256 s] instead of Cb.
template<int OUTBF, int GELU>
__global__ __launch_bounds__(256) void k_gemm(const __bf16* __restrict__ A,
                                              const __bf16* __restrict__ Bt,
                                              const float* __restrict__ bias,
                                              float* __restrict__ C,
                                              __bf16* __restrict__ Cb,
                                              __bf16* __restrict__ vtout,
                                              int K, int M) {
    __shared__ __align__(16) __bf16 As[128 * 32];
    __shared__ __align__(16) __bf16 Bs[128 * 32];
    const int tid = threadIdx.x;
    const int wid = tid >> 6, lane = tid & 63;
    const int rowbase = blockIdx.y * 128, colbase = blockIdx.x * 128;
    const int wr = wid >> 1, wc = wid & 1;
    const int lrow = lane & 15, lk = (lane >> 4) * 8;

    f32x4 acc[4][4];
#pragma unroll
    for (int m = 0; m < 4; m++)
#pragma unroll
        for (int n = 0; n < 4; n++) acc[m][n] = f32x4{0.f, 0.f, 0.f, 0.f};

    for (int k0 = 0; k0 < K; k0 += 32) {
#pragma unroll
        for (int p = 0; p < 2; p++) {
            int idx = tid + p * 256;               // 512 segs of 16B each
            int r = idx >> 2, cseg = idx & 3;
            GLOAD16(&A [(size_t)(rowbase + r) * K + k0 + cseg * 8], &As[idx * 8]);
            GLOAD16(&Bt[(size_t)(colbase + r) * K + k0 + cseg * 8], &Bs[idx * 8]);
        }
        __syncthreads();
        bf16x8 aF[4], bF[4];
#pragma unroll
        for (int m = 0; m < 4; m++) aF[m] = *(const bf16x8*)&As[(wr * 64 + m * 16 + lrow) * 32 + lk];
#pragma unroll
        for (int n = 0; n < 4; n++) bF[n] = *(const bf16x8*)&Bs[(wc * 64 + n * 16 + lrow) * 32 + lk];
#pragma unroll
        for (int m = 0; m < 4; m++)
#pragma unroll
            for (int n = 0; n < 4; n++)
                acc[m][n] = __builtin_amdgcn_mfma_f32_16x16x32_bf16(aF[m], bF[n], acc[m][n], 0, 0, 0);
        __syncthreads();
    }

    const bool dovt = (vtout != nullptr) && (colbase >= 1024);   // wave-uniform
#pragma unroll
    for (int m = 0; m < 4; m++) {
        int row = rowbase + wr * 64 + m * 16 + (lane >> 4) * 4;
#pragma unroll
        for (int n = 0; n < 4; n++) {
            int col = colbase + wc * 64 + n * 16 + (lane & 15);
            float bv = bias ? bias[col] : 0.0f;
            float v[4];
#pragma unroll
            for (int r = 0; r < 4; r++) {
                float x = acc[m][n][r] + bv;
                if (GELU) x = gelu_exact(x);
                v[r] = x;
            }
            if (dovt) {
                int hcol = col - 1024;
                int hh = hcol >> 6, d = hcol & 63;
                int bb = row >> 8, s0 = row & 255;
                u16x4 pk = { bf_bits(v[0]), bf_bits(v[1]), bf_bits(v[2]), bf_bits(v[3]) };
                *(u16x4*)&vtout[((size_t)((bb * 8 + hh) * 64 + d)) * 256 + s0] = pk;
            } else {
#pragma unroll
                for (int r = 0; r < 4; r++) {
                    if (OUTBF) Cb[(size_t)(row + r) * M + col] = (__bf16)v[r];
                    else       C [(size_t)(row + r) * M + col] = v[r];
                }
            }
        }
    }
}

// ---------------------------------------------------------------- MFMA fused attention
// grid: 2048 blocks = (bh, qtile); 4 waves, wave wid owns 16 q rows.
__global__ __launch_bounds__(256) void k_attn(const __bf16* __restrict__ QKV,
                                              const uint8_t* __restrict__ ebt,
                                              const float* __restrict__ mskadd,
                                              const __bf16* __restrict__ Vt,
                                              __bf16* __restrict__ T) {
    __shared__ __align__(16) char Ks[8192];
    __shared__ __align__(16) char Vs[8192];
    __shared__ __align__(16) char Ps[4][2048];
    __shared__ float Ma[256];
    const int blk = blockIdx.x;
    const int bh = blk >> 2, qt = blk & 3;
    const int b = bh >> 3, h = bh & 7;
    const int tid = threadIdx.x, wid = tid >> 6, lane = tid & 63;
    const int g = lane >> 4, c = lane & 15;

    Ma[tid] = mskadd[(b << 8) + tid];

    // Q fragments: A-operand for 16x16x32, lane holds Q[q=c][d=ks*32+g*8..+8]
    bf16x8 qf[2];
    {
        const __bf16* qrow = QKV + (size_t)((b << 8) + qt * 64 + wid * 16 + c) * 1536 + h * 64;
        qf[0] = *(const bf16x8*)(qrow + g * 8);
        qf[1] = *(const bf16x8*)(qrow + 32 + g * 8);
    }

    f32x4 oacc[4];
    float m_s[4], l_s[4];
#pragma unroll
    for (int r = 0; r < 4; r++) { m_s[r] = -1e30f; l_s[r] = 0.0f; }
#pragma unroll
    for (int nd = 0; nd < 4; nd++) oacc[nd] = f32x4{0.f, 0.f, 0.f, 0.f};

    for (int t = 0; t < 4; t++) {
        const int t0 = t * 64;
        __syncthreads();
#pragma unroll
        for (int p = 0; p < 2; p++) {
            int idx = tid + p * 256;
            int row = idx >> 3, c8 = idx & 7;
            int lds = row * 128 + ((c8 * 16) ^ ((row & 7) << 4));
            *(uint4*)(Ks + lds) = *(const uint4*)&QKV[(size_t)((b << 8) + t0 + row) * 1536 + 512 + h * 64 + c8 * 8];
            *(uint4*)(Vs + lds) = *(const uint4*)&Vt[((size_t)bh * 64 + row) * 256 + t0 + c8 * 8];
        }
        __syncthreads();

        bf16x8 kf[4][2], vb[4][2];
#pragma unroll
        for (int n = 0; n < 4; n++) {
            int row = n * 16 + c;
#pragma unroll
            for (int ks = 0; ks < 2; ks++) {
                int col = (g * 16 + ks * 64) ^ ((row & 7) << 4);
                kf[n][ks] = *(const bf16x8*)(Ks + row * 128 + col);
                vb[n][ks] = *(const bf16x8*)(Vs + row * 128 + col);
            }
        }

        f32x4 sa[4];
#pragma unroll
        for (int nk = 0; nk < 4; nk++) sa[nk] = f32x4{0.f, 0.f, 0.f, 0.f};
#pragma unroll
        for (int ks = 0; ks < 2; ks++)
#pragma unroll
            for (int nk = 0; nk < 4; nk++)
                sa[nk] = __builtin_amdgcn_mfma_f32_16x16x32_bf16(qf[ks], kf[nk][ks], sa[nk], 0, 0, 0);

        uint4 b4 = *(const uint4*)(ebt + ((((size_t)bh * 4 + t) * 4 + qt) * 4 + wid) * 1024 + c * 64 + g * 16);
        uint32_t bw[4] = { b4.x, b4.y, b4.z, b4.w };
        float s[4][4];                             // [nk][r]
#pragma unroll
        for (int nk = 0; nk < 4; nk++) {
            float ma = Ma[t0 + nk * 16 + c];
#pragma unroll
            for (int r = 0; r < 4; r++)
                s[nk][r] = sa[nk][r] * 0.125f + dec_e4m3((bw[r] >> (nk * 8)) & 0xFF) + ma;
        }

        float corr[4];
#pragma unroll
        for (int r = 0; r < 4; r++) {
            float tm = fmaxf(fmaxf(s[0][r], s[1][r]), fmaxf(s[2][r], s[3][r]));
#pragma unroll
            for (int off = 1; off < 16; off <<= 1)
                tm = fmaxf(tm, __shfl_xor(tm, off));
            float mnew = fmaxf(m_s[r], tm);
            corr[r] = __expf(m_s[r] - mnew);
            m_s[r] = mnew;
            float psum = 0.0f;
#pragma unroll
            for (int nk = 0; nk < 4; nk++) {
                s[nk][r] = __expf(s[nk][r] - mnew);
                psum += s[nk][r];
            }
#pragma unroll
            for (int off = 1; off < 16; off <<= 1)
                psum += __shfl_xor(psum, off);
            l_s[r] = l_s[r] * corr[r] + psum;
        }
#pragma unroll
        for (int nd = 0; nd < 4; nd++)
#pragma unroll
            for (int r = 0; r < 4; r++)
                oacc[nd][r] *= corr[r];

        // P -> per-wave LDS (bf16, swizzled), read back as A-fragments
        char* psw = Ps[wid];
#pragma unroll
        for (int r = 0; r < 4; r++) {
            int qs = g * 4 + r;
#pragma unroll
            for (int nk = 0; nk < 4; nk++)
                *(__bf16*)(psw + qs * 128 + ((nk * 32 + c * 2) ^ ((qs & 7) << 4))) = (__bf16)s[nk][r];
        }
        bf16x8 pa[2];
#pragma unroll
        for (int ks = 0; ks < 2; ks++)
            pa[ks] = *(const bf16x8*)(psw + c * 128 + ((g * 16 + ks * 64) ^ ((c & 7) << 4)));
#pragma unroll
        for (int nd = 0; nd < 4; nd++)
#pragma unroll
            for (int ks = 0; ks < 2; ks++)
                oacc[nd] = __builtin_amdgcn_mfma_f32_16x16x32_bf16(pa[ks], vb[nd][ks], oacc[nd], 0, 0, 0);
    }

#pragma unroll
    for (int r = 0; r < 4; r++) {
        float inv = 1.0f / l_s[r];
        size_t rowb = (size_t)((b << 8) + qt * 64 + wid * 16 + g * 4 + r) * 512 + h * 64 + c;
#pragma unroll
        for (int nd = 0; nd < 4; nd++)
            T[rowb + nd * 16] = (__bf16)(oacc[nd][r] * inv);
    }
}

// ---------------------------------------------------------------- residual + LayerNorm
__global__ __launch_bounds__(256) void k_ln(float* __restrict__ X, __bf16* __restrict__ Xb,
                                            const float* __restrict__ U,
                                            const float* __restrict__ g,
                                            const float* __restrict__ bb) {
    __shared__ float red[4];
    int row = blockIdx.x, t = threadIdx.x;
    size_t base = (size_t)row * D_;
    float v0 = X[base + t] + U[base + t];
    float v1 = X[base + t + 256] + U[base + t + 256];
    float s = wave_sum(v0 + v1);
    if ((t & 63) == 0) red[t >> 6] = s;
    __syncthreads();
    float mean = (red[0] + red[1] + red[2] + red[3]) * (1.0f / D_);
    float d0 = v0 - mean, d1 = v1 - mean;
    float s2 = wave_sum(d0 * d0 + d1 * d1);
    __syncthreads();
    if ((t & 63) == 0) red[t >> 6] = s2;
    __syncthreads();
    float var = (red[0] + red[1] + red[2] + red[3]) * (1.0f / D_);
    float rr = rsqrtf(var + EPS);
    float o0 = d0 * rr * g[t] + bb[t];
    float o1 = d1 * rr * g[t + 256] + bb[t + 256];
    X[base + t]        = o0;
    X[base + t + 256]  = o1;
    Xb[base + t]       = (__bf16)o0;
    Xb[base + t + 256] = (__bf16)o1;
}

// ---------------------------------------------------------------- MLP head on CLS
__global__ __launch_bounds__(256) void k_head(const float* __restrict__ X,
                                              const float* __restrict__ W1,
                                              const float* __restrict__ b1,
                                              const float* __restrict__ W2,
                                              const float* __restrict__ b2,
                                              float* __restrict__ out) {
    __shared__ float cls[D_];
    __shared__ float red[4];
    int b = blockIdx.x, t = threadIdx.x;
    size_t base = (size_t)(b << 8) * D_;
    cls[t]       = X[base + t];
    cls[t + 256] = X[base + t + 256];
    __syncthreads();
    float acc = 0.0f;
    for (int d = 0; d < D_; d++) acc = fmaf(cls[d], W1[(size_t)d * HID_ + t], acc);
    acc += b1[t];
    float hsum = wave_sum(gelu_exact(acc) * W2[t]);
    if ((t & 63) == 0) red[t >> 6] = hsum;
    __syncthreads();
    if (t == 0) out[b] = red[0] + red[1] + red[2] + red[3] + b2[0];
}

// ---------------------------------------------------------------- launch
extern "C" void kernel_launch(void* const* d_in, const int* in_sizes, int n_in,
                              void* d_out, int out_size, void* d_ws, size_t ws_size,
                              hipStream_t stream) {
    const float* atom = (const float*)d_in[0];
    const float* eb   = (const float*)d_in[1];
    const void*  mraw = d_in[2];
    const float* cls  = (const float*)d_in[3];
    const float* Wq = (const float*)d_in[4];  const float* bq = (const float*)d_in[5];
    const float* Wk = (const float*)d_in[6];  const float* bk = (const float*)d_in[7];
    const float* Wv = (const float*)d_in[8];  const float* bv = (const float*)d_in[9];
    const float* Wo = (const float*)d_in[10]; const float* bo = (const float*)d_in[11];
    const float* g1 = (const float*)d_in[12]; const float* be1 = (const float*)d_in[13];
    const float* W1 = (const float*)d_in[14]; const float* b1 = (const float*)d_in[15];
    const float* W2 = (const float*)d_in[16]; const float* b2 = (const float*)d_in[17];
    const float* g2 = (const float*)d_in[18]; const float* be2 = (const float*)d_in[19];
    const float* hW1 = (const float*)d_in[20]; const float* hb1 = (const float*)d_in[21];
    const float* hW2 = (const float*)d_in[22]; const float* hb2 = (const float*)d_in[23];
    float* out = (float*)d_out;

    // ---- workspace layout ----
    char* p = (char*)d_ws;
    float*  X     = (float*)p;                 p += (size_t)N_ * D_ * 4;
    float*  Ub    = (float*)p;                 p += (size_t)N_ * D_ * 4;        // also hosts Vt during attn
    __bf16* Xb    = (__bf16*)p;                p += (size_t)N_ * D_ * 2;
    char*   R     = p;                         p += (size_t)N_ * FF_ * 2;
    __bf16* QKVb  = (__bf16*)R;                                                 // [N][1536]
    __bf16* Tb    = (__bf16*)(R + (size_t)N_ * 1536 * 2);                       // [N][512]
    __bf16* Hb    = (__bf16*)R;                                                 // [N][2048]
    uint8_t* ebt  = (uint8_t*)p;               p += (size_t)B_ * H_ * SP * SP;  // fragment-layout fp8
    __bf16* Wqkvt = (__bf16*)p;                p += (size_t)L_ * 1536 * 512 * 2;
    __bf16* Wot   = (__bf16*)p;                p += (size_t)L_ * 512 * 512 * 2;
    __bf16* W1t   = (__bf16*)p;                p += (size_t)L_ * 2048 * 512 * 2;
    __bf16* W2t   = (__bf16*)p;                p += (size_t)L_ * 512 * 2048 * 2;
    float*  bqkv  = (float*)p;                 p += (size_t)L_ * 1536 * 4;
    float*  mskadd= (float*)p;                 p += (size_t)B_ * SP * 4;
    int* flag = (int*)p;
    __bf16* Vt = (__bf16*)Ub;                  // V^T scratch, live only during attention

    // ---- prep ----
    hipMemsetAsync(flag, 0, 4, stream);
    k_mask_detect<<<16, 256, 0, stream>>>((const unsigned int*)mraw, (B_ * S_) / 4, flag);
    k_mask_prep<<<(B_ * SP) / 256, 256, 0, stream>>>(mraw, flag, mskadd);
    k_bcat<<<(L_ * 1536) / 256, 256, 0, stream>>>(bq, bk, bv, bqkv);
    k_wt<<<dim3(8, 8, L_),  256, 0, stream>>>(Wq, Wqkvt, 512, 512, 0,    262144, 786432);
    k_wt<<<dim3(8, 8, L_),  256, 0, stream>>>(Wk, Wqkvt, 512, 512, 512,  262144, 786432);
    k_wt<<<dim3(8, 8, L_),  256, 0, stream>>>(Wv, Wqkvt, 512, 512, 1024, 262144, 786432);
    k_wt<<<dim3(8, 8, L_),  256, 0, stream>>>(Wo, Wot,   512, 512, 0,    262144, 262144);
    k_wt<<<dim3(32, 8, L_), 256, 0, stream>>>(W1, W1t,   512, 2048, 0,   1048576, 1048576);
    k_wt<<<dim3(8, 32, L_), 256, 0, stream>>>(W2, W2t,   2048, 512, 0,   1048576, 1048576);
    k_ebt4<<<B_ * SP, 256, 0, stream>>>(eb, ebt);
    k_build_x<<<(N_ * D_) / 256, 256, 0, stream>>>(atom, cls, X, Xb);

    dim3 gQKV(12, 128), gD(4, 128), gF1(16, 128);
    for (int l = 0; l < L_; l++) {
        k_gemm<1, 0><<<gQKV, 256, 0, stream>>>(Xb, Wqkvt + (size_t)l * 786432, bqkv + l * 1536,
                                               nullptr, QKVb, Vt, 512, 1536);
        k_attn<<<B_ * H_ * 4, 256, 0, stream>>>(QKVb, ebt, mskadd, Vt, Tb);
        k_gemm<0, 0><<<gD, 256, 0, stream>>>(Tb, Wot + (size_t)l * 262144, bo + l * 512,
                                             Ub, nullptr, nullptr, 512, 512);
        k_ln<<<N_, 256, 0, stream>>>(X, Xb, Ub, g1 + l * D_, be1 + l * D_);
        k_gemm<1, 1><<<gF1, 256, 0, stream>>>(Xb, W1t + (size_t)l * 1048576, b1 + l * FF_,
                                              nullptr, Hb, nullptr, 512, 2048);
        k_gemm<0, 0><<<gD, 256, 0, stream>>>(Hb, W2t + (size_t)l * 1048576, b2 + l * D_,
                                             Ub, nullptr, nullptr, 2048, 512);
        k_ln<<<N_, 256, 0, stream>>>(X, Xb, Ub, g2 + l * D_, be2 + l * D_);
    }
    k_head<<<B_, 256, 0, stream>>>(X, hW1, hb1, hW2, hb2, out);
}

// Round 5
// 1825.175 us; speedup vs baseline: 6.5795x; 1.0975x over previous
//
#include <hip/hip_runtime.h>
#include <math.h>
#include <stdint.h>

#define B_   64
#define S_   255
#define SP   256
#define D_   512
#define H_   8
#define L_   6
#define FF_  2048
#define HID_ 256
#define N_   (B_*SP)       // 16384 rows
#define EPS  1e-5f

using bf16x8 = __bf16 __attribute__((ext_vector_type(8)));
using f32x4  = float __attribute__((ext_vector_type(4)));
using u16x4  = unsigned short __attribute__((ext_vector_type(4)));

// ---------------------------------------------------------------- utilities
__device__ inline float wave_sum(float v) {
#pragma unroll
    for (int off = 32; off; off >>= 1) v += __shfl_xor(v, off);
    return v;
}

// fast exact-erf gelu: A&S 7.1.26 polynomial, |erf err| <= 1.5e-7
__device__ inline float gelu_exact(float x) {
    float z  = fabsf(x) * 0.70710678118654752f;
    float tt = __builtin_amdgcn_rcpf(fmaf(0.3275911f, z, 1.0f));
    float poly = tt * (0.254829592f + tt * (-0.284496736f + tt * (1.421413741f +
                 tt * (-1.453152027f + tt * 1.061405429f))));
    float er = 1.0f - poly * __expf(-z * z);
    er = copysignf(er, x);
    return 0.5f * x * (1.0f + er);
}

__device__ inline unsigned short bf_bits(float x) {
    __bf16 h = (__bf16)x;
    return *(unsigned short*)&h;
}

// fp8 e4m3fn encode (RNE) / decode
__device__ inline uint8_t enc_e4m3(float f) {
    uint32_t u = __float_as_uint(f);
    uint32_t s = (u >> 24) & 0x80u;
    float a = fabsf(f);
    if (a < 0.015625f) {
        int m = (int)rintf(a * 512.0f);
        if (m >= 8) return (uint8_t)(s | 0x08);
        return (uint8_t)(s | (uint32_t)m);
    }
    if (a > 448.0f) return (uint8_t)(s | 0x7E);
    uint32_t b = __float_as_uint(a);
    uint32_t expf_ = b >> 23;
    uint32_t mant = b & 0x7FFFFF;
    uint32_t keep = mant >> 20;
    uint32_t rest = mant & 0xFFFFF;
    if (rest > 0x80000u || (rest == 0x80000u && (keep & 1))) keep++;
    if (keep == 8) { keep = 0; expf_++; }
    int e8 = (int)expf_ - 120;
    if (e8 >= 16) return (uint8_t)(s | 0x7E);
    return (uint8_t)(s | ((uint32_t)e8 << 3) | keep);
}

__device__ inline float dec_e4m3(uint32_t b) {
    uint32_t mag = b & 0x7Fu;
    float fm = __uint_as_float((mag << 20) + (120u << 23));
    if ((mag >> 3) == 0) fm = fm * 2.0f - 0.015625f;
    return (b & 0x80u) ? -fm : fm;
}

// async global->LDS 16B (m97 recipe)
#define GLOAD16(gsrc, ldst) \
    __builtin_amdgcn_global_load_lds((const __attribute__((address_space(1))) unsigned int*)(gsrc), \
                                     (__attribute__((address_space(3))) unsigned int*)(ldst), 16, 0, 0)

// ---------------------------------------------------------------- build X = [cls; atom]
__global__ void k_build_x(const float* __restrict__ atom, const float* __restrict__ cls,
                          float* __restrict__ X, __bf16* __restrict__ Xb) {
    int idx = blockIdx.x * 256 + threadIdx.x;
    int col = idx & (D_ - 1);
    int row = idx >> 9;
    int sr  = row & (SP - 1);
    int b   = row >> 8;
    float v = (sr == 0) ? cls[col] : atom[((size_t)(b * S_) + (sr - 1)) * D_ + col];
    X[idx]  = v;
    Xb[idx] = (__bf16)v;
}

// ---------------------------------------------------------------- mask layout detection
__global__ void k_mask_detect(const unsigned int* __restrict__ mw, int nw, int* flag) {
    int i = blockIdx.x * 256 + threadIdx.x;
    if (i < nw && mw[i] > 1u) atomicOr(flag, 1);
}

__global__ void k_mask_prep(const void* __restrict__ mraw, const int* __restrict__ flag,
                            float* __restrict__ mskadd) {
    int i = blockIdx.x * 256 + threadIdx.x;
    int b = i >> 8, j = i & 255;
    float v = 0.0f;
    if (j > 0) {
        int src = b * S_ + (j - 1);
        bool m = (*flag) ? (((const unsigned char*)mraw)[src] != 0)
                         : (((const int*)mraw)[src] != 0);
        if (m) v = -1e30f;
    }
    mskadd[i] = v;
}

// ---------------------------------------------------------------- weight transpose+cast
__global__ __launch_bounds__(256) void k_wt(const float* __restrict__ W, __bf16* __restrict__ Wt,
                                            int K, int Mw, int mout_off,
                                            size_t in_lstride, size_t out_lstride) {
    __shared__ float T[64][65];
    int l = blockIdx.z;
    int m0 = blockIdx.x * 64, k0 = blockIdx.y * 64;
    const float* Wl = W + (size_t)l * in_lstride;
    __bf16* Wtl = Wt + (size_t)l * out_lstride;
    int tid = threadIdx.x;
    int cc = tid & 63, rr = tid >> 6;
#pragma unroll
    for (int p = 0; p < 16; p++) {
        int kk = rr + p * 4;
        T[kk][cc] = Wl[(size_t)(k0 + kk) * Mw + m0 + cc];
    }
    __syncthreads();
#pragma unroll
    for (int p = 0; p < 16; p++) {
        int mm = rr + p * 4;
        Wtl[(size_t)(mout_off + m0 + mm) * K + k0 + cc] = (__bf16)T[cc][mm];
    }
}

// ---------------------------------------------------------------- qkv bias concat
__global__ void k_bcat(const float* __restrict__ bq, const float* __restrict__ bk,
                       const float* __restrict__ bv, float* __restrict__ bqkv) {
    int i = blockIdx.x * 256 + threadIdx.x;
    int l = i / 1536, c = i % 1536;
    float v;
    if (c < 512)       v = bq[l * 512 + c];
    else if (c < 1024) v = bk[l * 512 + c - 512];
    else               v = bv[l * 512 + c - 1024];
    bqkv[i] = v;
}

// ---------------------------------------------------------------- bias repack, coalesced both sides
// block = (b, w, mq) owns q = w*64+mq*16+qi (qi=0..15). Output dword low bits = tid -> coalesced.
// dword x = ((((b*8+h)*4 + tl)*4 + w)*4 + mq)*256 + cc*16 + qi ; byte nk -> key k = tl*64+nk*16+cc
__global__ __launch_bounds__(256) void k_ebt5(const float* __restrict__ eb, uint8_t* __restrict__ ebt) {
    __shared__ uint8_t Ls[8 * 16 * 260];           // [h][qi][260], odd-dword qi stride
    int blk = blockIdx.x;                          // 64*16
    int b = blk >> 4, wm = blk & 15;
    int w = wm >> 2, mq = wm & 3;
    int qbase = w * 64 + mq * 16;
    int t = threadIdx.x;
    for (int qi = 0; qi < 16; qi++) {
        int q = qbase + qi;
        if (q > 0) {
            const float4* src = (const float4*)(eb + ((size_t)(b * 255) + (q - 1)) * 2040);
#pragma unroll
            for (int p = 0; p < 2; p++) {
                int idx4 = t + p * 256;
                if (idx4 < 510) {
                    float4 v = src[idx4];
                    int k  = idx4 >> 1;
                    int h0 = (idx4 & 1) * 4;
                    Ls[((h0 + 0) * 16 + qi) * 260 + k] = enc_e4m3(v.x);
                    Ls[((h0 + 1) * 16 + qi) * 260 + k] = enc_e4m3(v.y);
                    Ls[((h0 + 2) * 16 + qi) * 260 + k] = enc_e4m3(v.z);
                    Ls[((h0 + 3) * 16 + qi) * 260 + k] = enc_e4m3(v.w);
                }
            }
        }
    }
    __syncthreads();
    int cc = t >> 4, qi = t & 15;
    int q = qbase + qi;
    uint32_t* outp = (uint32_t*)ebt;
#pragma unroll
    for (int h = 0; h < 8; h++) {
#pragma unroll
        for (int tl = 0; tl < 4; tl++) {
            uint32_t d = 0;
            if (q > 0) {
#pragma unroll
                for (int nk = 0; nk < 4; nk++) {
                    int k = tl * 64 + nk * 16 + cc;
                    if (k > 0) d |= (uint32_t)Ls[(h * 16 + qi) * 260 + (k - 1)] << (nk * 8);
                }
            }
            size_t x = ((((size_t)(b * 8 + h) * 4 + tl) * 4 + w) * 4 + mq) * 256 + t;
            outp[x] = d;
        }
    }
}

// ---------------------------------------------------------------- bf16 MFMA GEMM
// A [N][K] bf16; Bt [M][K] bf16; 128x128 tile, 4 waves, BK=32, global_load_lds staging.
// RES: add Xres f32 (M must be 512). vtout: colbase>=1024 blocks write V^T instead of Cb.
template<int OUTBF, int GELU, int RES>
__global__ __launch_bounds__(256) void k_gemm(const __bf16* __restrict__ A,
                                              const __bf16* __restrict__ Bt,
                                              const float* __restrict__ bias,
                                              float* __restrict__ C,
                                              __bf16* __restrict__ Cb,
                                              __bf16* __restrict__ vtout,
                                              const float* __restrict__ Xres,
                                              int K, int M) {
    __shared__ __align__(16) __bf16 As[128 * 32];
    __shared__ __align__(16) __bf16 Bs[128 * 32];
    const int tid = threadIdx.x;
    const int wid = tid >> 6, lane = tid & 63;
    const int rowbase = blockIdx.y * 128, colbase = blockIdx.x * 128;
    const int wr = wid >> 1, wc = wid & 1;
    const int lrow = lane & 15, lk = (lane >> 4) * 8;

    f32x4 acc[4][4];
#pragma unroll
    for (int m = 0; m < 4; m++)
#pragma unroll
        for (int n = 0; n < 4; n++) acc[m][n] = f32x4{0.f, 0.f, 0.f, 0.f};

    for (int k0 = 0; k0 < K; k0 += 32) {
#pragma unroll
        for (int p = 0; p < 2; p++) {
            int idx = tid + p * 256;               // 512 segs of 16B each
            int r = idx >> 2, cseg = idx & 3;
            GLOAD16(&A [(size_t)(rowbase + r) * K + k0 + cseg * 8], &As[idx * 8]);
            GLOAD16(&Bt[(size_t)(colbase + r) * K + k0 + cseg * 8], &Bs[idx * 8]);
        }
        __syncthreads();
        bf16x8 aF[4], bF[4];
#pragma unroll
        for (int m = 0; m < 4; m++) aF[m] = *(const bf16x8*)&As[(wr * 64 + m * 16 + lrow) * 32 + lk];
#pragma unroll
        for (int n = 0; n < 4; n++) bF[n] = *(const bf16x8*)&Bs[(wc * 64 + n * 16 + lrow) * 32 + lk];
#pragma unroll
        for (int m = 0; m < 4; m++)
#pragma unroll
            for (int n = 0; n < 4; n++)
                acc[m][n] = __builtin_amdgcn_mfma_f32_16x16x32_bf16(aF[m], bF[n], acc[m][n], 0, 0, 0);
        __syncthreads();
    }

    const bool dovt = (vtout != nullptr) && (colbase >= 1024);   // wave-uniform
#pragma unroll
    for (int m = 0; m < 4; m++) {
        int row = rowbase + wr * 64 + m * 16 + (lane >> 4) * 4;
#pragma unroll
        for (int n = 0; n < 4; n++) {
            int col = colbase + wc * 64 + n * 16 + (lane & 15);
            float bv = bias ? bias[col] : 0.0f;
            float v[4];
#pragma unroll
            for (int r = 0; r < 4; r++) {
                float x = acc[m][n][r] + bv;
                if (GELU) x = gelu_exact(x);
                if (RES)  x += Xres[(size_t)(row + r) * 512 + col];
                v[r] = x;
            }
            if (dovt) {
                int hcol = col - 1024;
                int hh = hcol >> 6, d = hcol & 63;
                int bb = row >> 8, s0 = row & 255;
                u16x4 pk = { bf_bits(v[0]), bf_bits(v[1]), bf_bits(v[2]), bf_bits(v[3]) };
                *(u16x4*)&vtout[((size_t)((bb * 8 + hh) * 64 + d)) * 256 + s0] = pk;
            } else {
#pragma unroll
                for (int r = 0; r < 4; r++) {
                    if (OUTBF) Cb[(size_t)(row + r) * M + col] = (__bf16)v[r];
                    else       C [(size_t)(row + r) * M + col] = v[r];
                }
            }
        }
    }
}

// ---------------------------------------------------------------- MFMA fused attention
// grid: 2048 blocks = (bh, qtile); 4 waves, wave wid owns 16 q rows.
__global__ __launch_bounds__(256) void k_attn(const __bf16* __restrict__ QKV,
                                              const uint8_t* __restrict__ ebt,
                                              const float* __restrict__ mskadd,
                                              const __bf16* __restrict__ Vt,
                                              __bf16* __restrict__ T) {
    __shared__ __align__(16) char Ks[8192];
    __shared__ __align__(16) char Vs[8192];
    __shared__ __align__(16) char Ps[4][2048];
    __shared__ float Ma[256];
    const int blk = blockIdx.x;
    const int bh = blk >> 2, qt = blk & 3;
    const int b = bh >> 3, h = bh & 7;
    const int tid = threadIdx.x, wid = tid >> 6, lane = tid & 63;
    const int g = lane >> 4, c = lane & 15;

    Ma[tid] = mskadd[(b << 8) + tid];

    bf16x8 qf[2];
    {
        const __bf16* qrow = QKV + (size_t)((b << 8) + qt * 64 + wid * 16 + c) * 1536 + h * 64;
        qf[0] = *(const bf16x8*)(qrow + g * 8);
        qf[1] = *(const bf16x8*)(qrow + 32 + g * 8);
    }

    f32x4 oacc[4];
    float m_s[4], l_s[4];
#pragma unroll
    for (int r = 0; r < 4; r++) { m_s[r] = -1e30f; l_s[r] = 0.0f; }
#pragma unroll
    for (int nd = 0; nd < 4; nd++) oacc[nd] = f32x4{0.f, 0.f, 0.f, 0.f};

    for (int t = 0; t < 4; t++) {
        const int t0 = t * 64;
        __syncthreads();
#pragma unroll
        for (int p = 0; p < 2; p++) {
            int idx = tid + p * 256;
            int row = idx >> 3, c8 = idx & 7;
            int lds = row * 128 + ((c8 * 16) ^ ((row & 7) << 4));
            *(uint4*)(Ks + lds) = *(const uint4*)&QKV[(size_t)((b << 8) + t0 + row) * 1536 + 512 + h * 64 + c8 * 8];
            *(uint4*)(Vs + lds) = *(const uint4*)&Vt[((size_t)bh * 64 + row) * 256 + t0 + c8 * 8];
        }
        __syncthreads();

        bf16x8 kf[4][2], vb[4][2];
#pragma unroll
        for (int n = 0; n < 4; n++) {
            int row = n * 16 + c;
#pragma unroll
            for (int ks = 0; ks < 2; ks++) {
                int col = (g * 16 + ks * 64) ^ ((row & 7) << 4);
                kf[n][ks] = *(const bf16x8*)(Ks + row * 128 + col);
                vb[n][ks] = *(const bf16x8*)(Vs + row * 128 + col);
            }
        }

        f32x4 sa[4];
#pragma unroll
        for (int nk = 0; nk < 4; nk++) sa[nk] = f32x4{0.f, 0.f, 0.f, 0.f};
#pragma unroll
        for (int ks = 0; ks < 2; ks++)
#pragma unroll
            for (int nk = 0; nk < 4; nk++)
                sa[nk] = __builtin_amdgcn_mfma_f32_16x16x32_bf16(qf[ks], kf[nk][ks], sa[nk], 0, 0, 0);

        uint4 b4 = *(const uint4*)(ebt + ((((size_t)bh * 4 + t) * 4 + qt) * 4 + wid) * 1024 + c * 64 + g * 16);
        uint32_t bw[4] = { b4.x, b4.y, b4.z, b4.w };
        float s[4][4];                             // [nk][r]
#pragma unroll
        for (int nk = 0; nk < 4; nk++) {
            float ma = Ma[t0 + nk * 16 + c];
#pragma unroll
            for (int r = 0; r < 4; r++)
                s[nk][r] = sa[nk][r] * 0.125f + dec_e4m3((bw[r] >> (nk * 8)) & 0xFF) + ma;
        }

        float corr[4];
#pragma unroll
        for (int r = 0; r < 4; r++) {
            float tm = fmaxf(fmaxf(s[0][r], s[1][r]), fmaxf(s[2][r], s[3][r]));
#pragma unroll
            for (int off = 1; off < 16; off <<= 1)
                tm = fmaxf(tm, __shfl_xor(tm, off));
            float mnew = fmaxf(m_s[r], tm);
            corr[r] = __expf(m_s[r] - mnew);
            m_s[r] = mnew;
            float psum = 0.0f;
#pragma unroll
            for (int nk = 0; nk < 4; nk++) {
                s[nk][r] = __expf(s[nk][r] - mnew);
                psum += s[nk][r];
            }
#pragma unroll
            for (int off = 1; off < 16; off <<= 1)
                psum += __shfl_xor(psum, off);
            l_s[r] = l_s[r] * corr[r] + psum;
        }
#pragma unroll
        for (int nd = 0; nd < 4; nd++)
#pragma unroll
            for (int r = 0; r < 4; r++)
                oacc[nd][r] *= corr[r];

        char* psw = Ps[wid];
#pragma unroll
        for (int r = 0; r < 4; r++) {
            int qs = g * 4 + r;
#pragma unroll
            for (int nk = 0; nk < 4; nk++)
                *(__bf16*)(psw + qs * 128 + ((nk * 32 + c * 2) ^ ((qs & 7) << 4))) = (__bf16)s[nk][r];
        }
        bf16x8 pa[2];
#pragma unroll
        for (int ks = 0; ks < 2; ks++)
            pa[ks] = *(const bf16x8*)(psw + c * 128 + ((g * 16 + ks * 64) ^ ((c & 7) << 4)));
#pragma unroll
        for (int nd = 0; nd < 4; nd++)
#pragma unroll
            for (int ks = 0; ks < 2; ks++)
                oacc[nd] = __builtin_amdgcn_mfma_f32_16x16x32_bf16(pa[ks], vb[nd][ks], oacc[nd], 0, 0, 0);
    }

#pragma unroll
    for (int r = 0; r < 4; r++) {
        float inv = 1.0f / l_s[r];
        size_t rowb = (size_t)((b << 8) + qt * 64 + wid * 16 + g * 4 + r) * 512 + h * 64 + c;
#pragma unroll
        for (int nd = 0; nd < 4; nd++)
            T[rowb + nd * 16] = (__bf16)(oacc[nd][r] * inv);
    }
}

// ---------------------------------------------------------------- LayerNorm of pre-summed U
__global__ __launch_bounds__(256) void k_ln2(const float* __restrict__ U,
                                             float* __restrict__ X, __bf16* __restrict__ Xb,
                                             const float* __restrict__ g,
                                             const float* __restrict__ bb) {
    __shared__ float red[4];
    int row = blockIdx.x, t = threadIdx.x;
    size_t base = (size_t)row * D_;
    float v0 = U[base + t];
    float v1 = U[base + t + 256];
    float s = wave_sum(v0 + v1);
    if ((t & 63) == 0) red[t >> 6] = s;
    __syncthreads();
    float mean = (red[0] + red[1] + red[2] + red[3]) * (1.0f / D_);
    float d0 = v0 - mean, d1 = v1 - mean;
    float s2 = wave_sum(d0 * d0 + d1 * d1);
    __syncthreads();
    if ((t & 63) == 0) red[t >> 6] = s2;
    __syncthreads();
    float var = (red[0] + red[1] + red[2] + red[3]) * (1.0f / D_);
    float rr = rsqrtf(var + EPS);
    float o0 = d0 * rr * g[t] + bb[t];
    float o1 = d1 * rr * g[t + 256] + bb[t + 256];
    X[base + t]        = o0;
    X[base + t + 256]  = o1;
    Xb[base + t]       = (__bf16)o0;
    Xb[base + t + 256] = (__bf16)o1;
}

// ---------------------------------------------------------------- MLP head on CLS
__global__ __launch_bounds__(256) void k_head(const float* __restrict__ X,
                                              const float* __restrict__ W1,
                                              const float* __restrict__ b1,
                                              const float* __restrict__ W2,
                                              const float* __restrict__ b2,
                                              float* __restrict__ out) {
    __shared__ float cls[D_];
    __shared__ float red[4];
    int b = blockIdx.x, t = threadIdx.x;
    size_t base = (size_t)(b << 8) * D_;
    cls[t]       = X[base + t];
    cls[t + 256] = X[base + t + 256];
    __syncthreads();
    float acc = 0.0f;
    for (int d = 0; d < D_; d++) acc = fmaf(cls[d], W1[(size_t)d * HID_ + t], acc);
    acc += b1[t];
    float hsum = wave_sum(gelu_exact(acc) * W2[t]);
    if ((t & 63) == 0) red[t >> 6] = hsum;
    __syncthreads();
    if (t == 0) out[b] = red[0] + red[1] + red[2] + red[3] + b2[0];
}

// ---------------------------------------------------------------- launch
extern "C" void kernel_launch(void* const* d_in, const int* in_sizes, int n_in,
                              void* d_out, int out_size, void* d_ws, size_t ws_size,
                              hipStream_t stream) {
    const float* atom = (const float*)d_in[0];
    const float* eb   = (const float*)d_in[1];
    const void*  mraw = d_in[2];
    const float* cls  = (const float*)d_in[3];
    const float* Wq = (const float*)d_in[4];  const float* bq = (const float*)d_in[5];
    const float* Wk = (const float*)d_in[6];  const float* bk = (const float*)d_in[7];
    const float* Wv = (const float*)d_in[8];  const float* bv = (const float*)d_in[9];
    const float* Wo = (const float*)d_in[10]; const float* bo = (const float*)d_in[11];
    const float* g1 = (const float*)d_in[12]; const float* be1 = (const float*)d_in[13];
    const float* W1 = (const float*)d_in[14]; const float* b1 = (const float*)d_in[15];
    const float* W2 = (const float*)d_in[16]; const float* b2 = (const float*)d_in[17];
    const float* g2 = (const float*)d_in[18]; const float* be2 = (const float*)d_in[19];
    const float* hW1 = (const float*)d_in[20]; const float* hb1 = (const float*)d_in[21];
    const float* hW2 = (const float*)d_in[22]; const float* hb2 = (const float*)d_in[23];
    float* out = (float*)d_out;

    // ---- workspace layout ----
    char* p = (char*)d_ws;
    float*  X     = (float*)p;                 p += (size_t)N_ * D_ * 4;
    float*  Ub    = (float*)p;                 p += (size_t)N_ * D_ * 4;        // also hosts Vt during attn
    __bf16* Xb    = (__bf16*)p;                p += (size_t)N_ * D_ * 2;
    char*   R     = p;                         p += (size_t)N_ * FF_ * 2;
    __bf16* QKVb  = (__bf16*)R;                                                 // [N][1536]
    __bf16* Tb    = (__bf16*)(R + (size_t)N_ * 1536 * 2);                       // [N][512]
    __bf16* Hb    = (__bf16*)R;                                                 // [N][2048]
    uint8_t* ebt  = (uint8_t*)p;               p += (size_t)B_ * H_ * SP * SP;  // fragment-layout fp8
    __bf16* Wqkvt = (__bf16*)p;                p += (size_t)L_ * 1536 * 512 * 2;
    __bf16* Wot   = (__bf16*)p;                p += (size_t)L_ * 512 * 512 * 2;
    __bf16* W1t   = (__bf16*)p;                p += (size_t)L_ * 2048 * 512 * 2;
    __bf16* W2t   = (__bf16*)p;                p += (size_t)L_ * 512 * 2048 * 2;
    float*  bqkv  = (float*)p;                 p += (size_t)L_ * 1536 * 4;
    float*  mskadd= (float*)p;                 p += (size_t)B_ * SP * 4;
    int* flag = (int*)p;
    __bf16* Vt = (__bf16*)Ub;                  // V^T scratch, live only during attention

    // ---- prep ----
    hipMemsetAsync(flag, 0, 4, stream);
    k_mask_detect<<<16, 256, 0, stream>>>((const unsigned int*)mraw, (B_ * S_) / 4, flag);
    k_mask_prep<<<(B_ * SP) / 256, 256, 0, stream>>>(mraw, flag, mskadd);
    k_bcat<<<(L_ * 1536) / 256, 256, 0, stream>>>(bq, bk, bv, bqkv);
    k_wt<<<dim3(8, 8, L_),  256, 0, stream>>>(Wq, Wqkvt, 512, 512, 0,    262144, 786432);
    k_wt<<<dim3(8, 8, L_),  256, 0, stream>>>(Wk, Wqkvt, 512, 512, 512,  262144, 786432);
    k_wt<<<dim3(8, 8, L_),  256, 0, stream>>>(Wv, Wqkvt, 512, 512, 1024, 262144, 786432);
    k_wt<<<dim3(8, 8, L_),  256, 0, stream>>>(Wo, Wot,   512, 512, 0,    262144, 262144);
    k_wt<<<dim3(32, 8, L_), 256, 0, stream>>>(W1, W1t,   512, 2048, 0,   1048576, 1048576);
    k_wt<<<dim3(8, 32, L_), 256, 0, stream>>>(W2, W2t,   2048, 512, 0,   1048576, 1048576);
    k_ebt5<<<B_ * 16, 256, 0, stream>>>(eb, ebt);
    k_build_x<<<(N_ * D_) / 256, 256, 0, stream>>>(atom, cls, X, Xb);

    dim3 gQKV(12, 128), gD(4, 128), gF1(16, 128);
    for (int l = 0; l < L_; l++) {
        k_gemm<1, 0, 0><<<gQKV, 256, 0, stream>>>(Xb, Wqkvt + (size_t)l * 786432, bqkv + l * 1536,
                                                  nullptr, QKVb, Vt, nullptr, 512, 1536);
        k_attn<<<B_ * H_ * 4, 256, 0, stream>>>(QKVb, ebt, mskadd, Vt, Tb);
        k_gemm<0, 0, 1><<<gD, 256, 0, stream>>>(Tb, Wot + (size_t)l * 262144, bo + l * 512,
                                                Ub, nullptr, nullptr, X, 512, 512);
        k_ln2<<<N_, 256, 0, stream>>>(Ub, X, Xb, g1 + l * D_, be1 + l * D_);
        k_gemm<1, 1, 0><<<gF1, 256, 0, stream>>>(Xb, W1t + (size_t)l * 1048576, b1 + l * FF_,
                                                 nullptr, Hb, nullptr, nullptr, 512, 2048);
        k_gemm<0, 0, 1><<<gD, 256, 0, stream>>>(Hb, W2t + (size_t)l * 1048576, b2 + l * D_,
                                                Ub, nullptr, nullptr, X, 2048, 512);
        k_ln2<<<N_, 256, 0, stream>>>(Ub, X, Xb, g2 + l * D_, be2 + l * D_);
    }
    k_head<<<B_, 256, 0, stream>>>(X, hW1, hb1, hW2, hb2, out);
}